// Round 6
// baseline (2060.955 us; speedup 1.0000x reference)
//
#include <hip/hip_runtime.h>
#include <math.h>

#define NN 4096
#define FF 128
#define CD 100
#define OT_ITERS 20
#define RVAL (1.0f/4096.0f)
#define EK 8192
#define KS 16
#define CHUNK 32
#define NCH 128

typedef unsigned int uint;
typedef unsigned char uchar;
typedef __attribute__((ext_vector_type(8))) short bf16x8;
typedef __attribute__((ext_vector_type(4))) float f32x4;

// ---------- bf16 helpers ----------
__device__ __forceinline__ float bflo(uint u){ return __uint_as_float(u << 16); }
__device__ __forceinline__ float bfhi(uint u){ return __uint_as_float(u & 0xFFFF0000u); }
__device__ __forceinline__ unsigned short f2bf(float x){
  uint u = __float_as_uint(x);
  u += 0x7FFFu + ((u >> 16) & 1u);
  return (unsigned short)(u >> 16);
}
__device__ __forceinline__ void unpack8(uint4 kk, float* e){
  e[0]=bflo(kk.x); e[1]=bfhi(kk.x); e[2]=bflo(kk.y); e[3]=bfhi(kk.y);
  e[4]=bflo(kk.z); e[5]=bfhi(kk.z); e[6]=bflo(kk.w); e[7]=bfhi(kk.w);
}
__device__ __forceinline__ uint4 pack8(const float* e){
  union { unsigned short us[8]; uint4 u4; } pk;
#pragma unroll
  for (int k=0;k<8;++k) pk.us[k]=f2bf(e[k]);
  return pk.u4;
}

// ---------- ordered-float key encoding for atomic min/max ----------
__device__ __forceinline__ uint fkey(float f){
  uint u = __float_as_uint(f);
  return (u & 0x80000000u) ? ~u : (u | 0x80000000u);
}
__device__ __forceinline__ float fdec(uint k){
  uint u = (k & 0x80000000u) ? (k & 0x7FFFFFFFu) : ~k;
  return __uint_as_float(u);
}

// ---------- fp8 e4m3 (restricted domain K in [~0.36, ~1.01], always normal) ----------
__device__ __forceinline__ uint e8(float f){
  uint u = __float_as_uint(f);
  uint m23 = u & 0x7FFFFFu;
  uint rnd = 0x7FFFFu + ((m23 >> 20) & 1u);
  uint mr  = m23 + rnd;
  uint e   = (u >> 23) & 0xFFu;
  uint m3  = (mr >> 20) & 7u;
  e += (mr >> 23);
  return (((e - 120u) << 3) | m3) & 0x7Fu;
}
__device__ __forceinline__ void d8x4(uint w, float* e){
  e[0]=__uint_as_float((( w      & 0x7Fu)<<20)+0x3C000000u);
  e[1]=__uint_as_float((((w>> 8) & 0x7Fu)<<20)+0x3C000000u);
  e[2]=__uint_as_float((((w>>16) & 0x7Fu)<<20)+0x3C000000u);
  e[3]=__uint_as_float((((w>>24) & 0x7Fu)<<20)+0x3C000000u);
}

// ---------- wave/block reduce helpers (wave = 64) ----------
__device__ __forceinline__ float waveSum(float v){
#pragma unroll
  for (int o=32;o>0;o>>=1) v += __shfl_down(v,o);
  return v;
}
__device__ __forceinline__ float waveMax(float v){
#pragma unroll
  for (int o=32;o>0;o>>=1) v = fmaxf(v,__shfl_down(v,o));
  return v;
}
__device__ __forceinline__ float blkSum(float v, float* red){
  v = waveSum(v);
  if ((threadIdx.x&63)==0) red[threadIdx.x>>6] = v;
  __syncthreads();
  float r = red[0]+red[1]+red[2]+red[3];
  __syncthreads();
  return r;
}
__device__ __forceinline__ float blkMax(float v, float* red){
  v = waveMax(v);
  if ((threadIdx.x&63)==0) red[threadIdx.x>>6] = v;
  __syncthreads();
  float r = fmaxf(fmaxf(red[0],red[1]),fmaxf(red[2],red[3]));
  __syncthreads();
  return r;
}

// ---------- W transpose+convert: Wt[n][k] bf16 from W[k][n] fp32 ----------
__global__ __launch_bounds__(256) void transposeW(const float* __restrict__ W,
                                                  unsigned short* __restrict__ Wt)
{
  __shared__ unsigned short T[128][72];
  const int k0 = blockIdx.x*64, tid = threadIdx.x;
#pragma unroll
  for (int it=0; it<8; ++it){
    int f = tid + it*256;
    int r = f >> 5, c4 = f & 31;
    float4 v = *(const float4*)&W[(size_t)(k0+r)*FF + c4*4];
    T[c4*4+0][r]=f2bf(v.x); T[c4*4+1][r]=f2bf(v.y);
    T[c4*4+2][r]=f2bf(v.z); T[c4*4+3][r]=f2bf(v.w);
  }
  __syncthreads();
#pragma unroll
  for (int it=0; it<4; ++it){
    int f = tid + it*256;
    int n = f >> 3, c8 = f & 7;
    *(uint4*)&Wt[(size_t)n*EK + k0 + c8*8] = *(uint4*)&T[n][c8*8];
  }
}

// ---------- MFMA embed GEMM (split-K=16): part[ks][4096][128] ----------
__global__ __launch_bounds__(256) void embed_mfma(const float* __restrict__ A,
                                                  const unsigned short* __restrict__ Wt,
                                                  float* __restrict__ part)
{
  __shared__ unsigned short Al[64][72];
  __shared__ unsigned short Wl[128][72];
  const int tid = threadIdx.x;
  const int m0 = blockIdx.x * 64;
  const int kc = blockIdx.y * (EK/KS);
  const int w = tid >> 6, l = tid & 63;
  const int wr = w >> 1, wc = w & 1;
  const int lrow = l & 15, lk = (l >> 4) * 8;
  f32x4 acc[2][4];
#pragma unroll
  for (int mi=0;mi<2;++mi)
#pragma unroll
    for (int ni=0;ni<4;++ni) acc[mi][ni] = (f32x4){0.f,0.f,0.f,0.f};

  for (int k0 = kc; k0 < kc + EK/KS; k0 += 64) {
#pragma unroll
    for (int it = 0; it < 4; ++it) {
      int f = tid + it*256;
      int r = f >> 4, c4 = f & 15;
      float4 a4 = *(const float4*)&A[(size_t)(m0+r)*EK + k0 + c4*4];
      union { unsigned short us[4]; uint2 u2; } pk;
      pk.us[0]=f2bf(a4.x); pk.us[1]=f2bf(a4.y); pk.us[2]=f2bf(a4.z); pk.us[3]=f2bf(a4.w);
      *(uint2*)&Al[r][c4*4] = pk.u2;
    }
#pragma unroll
    for (int it = 0; it < 4; ++it) {
      int f = tid + it*256;
      int r = f >> 3, c8 = f & 7;
      *(uint4*)&Wl[r][c8*8] = *(const uint4*)&Wt[(size_t)r*EK + k0 + c8*8];
    }
    __syncthreads();
#pragma unroll
    for (int ksub = 0; ksub < 2; ++ksub) {
      bf16x8 af[2], bfr[4];
#pragma unroll
      for (int mi=0;mi<2;++mi) af[mi] = *(bf16x8*)&Al[wr*32+mi*16+lrow][ksub*32+lk];
#pragma unroll
      for (int ni=0;ni<4;++ni) bfr[ni] = *(bf16x8*)&Wl[wc*64+ni*16+lrow][ksub*32+lk];
#pragma unroll
      for (int mi=0;mi<2;++mi)
#pragma unroll
        for (int ni=0;ni<4;++ni)
          acc[mi][ni] = __builtin_amdgcn_mfma_f32_16x16x32_bf16(af[mi], bfr[ni], acc[mi][ni], 0,0,0);
    }
    __syncthreads();
  }
#pragma unroll
  for (int mi=0;mi<2;++mi)
#pragma unroll
    for (int ni=0;ni<4;++ni)
#pragma unroll
      for (int r=0;r<4;++r) {
        int row = m0 + wr*32 + mi*16 + (l>>4)*4 + r;
        int col = wc*64 + ni*16 + lrow;
        part[((size_t)blockIdx.y*NN + row)*FF + col] = acc[mi][ni][r];
      }
}

// ---------- reduce split-K partials + bias + l2norm -> fp32 and bf16 ----------
__global__ __launch_bounds__(128) void reduce_l2(const float* __restrict__ part,
                                                 const float* __restrict__ bias,
                                                 float* __restrict__ out,
                                                 unsigned short* __restrict__ outb)
{
  __shared__ float red[2];
  int i = blockIdx.x, t = threadIdx.x;
  float s = bias[t];
#pragma unroll
  for (int ks=0; ks<KS; ++ks) s += part[((size_t)ks*NN + i)*FF + t];
  float q = waveSum(s*s);
  if ((t&63)==0) red[t>>6]=q;
  __syncthreads();
  float val = s / sqrtf(red[0]+red[1]);
  out[(size_t)i*FF+t] = val;
  outb[(size_t)i*FF+t] = f2bf(val);
}

// ---------- softmax rows of l[4096x100] -> S, w = ||S_row|| ----------
__global__ __launch_bounds__(128) void softmax_rows(const float* __restrict__ l,
                                                    float* __restrict__ S,
                                                    float* __restrict__ w)
{
  __shared__ float sm[2], ss[2], sq[2];
  int i = blockIdx.x, t = threadIdx.x;
  int lane = t & 63, wid = t >> 6;
  float x = (t < CD) ? l[(size_t)i*CD + t] : -3.4e38f;
  float m = waveMax(x);
  if (lane==0) sm[wid]=m;
  __syncthreads();
  m = fmaxf(sm[0], sm[1]);
  float e = (t < CD) ? __expf(x - m) : 0.f;
  float s = waveSum(e);
  if (lane==0) ss[wid]=s;
  __syncthreads();
  float tot = ss[0]+ss[1];
  float sv = e / tot;
  if (t < CD) S[(size_t)i*CD + t] = sv;
  float q = waveSum(sv*sv);
  if (lane==0) sq[wid]=q;
  __syncthreads();
  if (t==0) w[i] = sqrtf(sq[0]+sq[1]);
}

// ---------- branchless sorted-descending top-7 insert ----------
__device__ __forceinline__ void ins7(float* b, int* ix, float cv, int j){
#pragma unroll
  for (int k=6;k>0;--k){
    bool any = cv > b[k];
    bool up  = cv > b[k-1];
    float nb = up ? b[k-1] : cv;
    int   nj = up ? ix[k-1] : j;
    b[k]  = any ? nb : b[k];
    ix[k] = any ? nj : ix[k];
  }
  if (cv > b[0]){ b[0] = cv; ix[0] = j; }
}

// ---------- fused knn: cos similarities + online top-7, no D matrix ----------
__global__ __launch_bounds__(256) void knn_fused(const float* __restrict__ S,
                                                 const float* __restrict__ w,
                                                 int* __restrict__ idx)
{
  __shared__ float Si[16][100];
  __shared__ float Sj[512][21];
  __shared__ float wj[512];
  __shared__ float wi[16];
  const int bk = blockIdx.x, t = threadIdx.x;
  const int i0 = bk*16;
  const int rg = t>>6, ct = t&63;
  for (int f=t; f<400; f+=256){
    int r=f/25, c4=f%25;
    *(float4*)&Si[r][c4*4] = *(const float4*)&S[(size_t)(i0+r)*CD + c4*4];
  }
  if (t<16) wi[t] = w[i0+t];
  float bv[4][7]; int bj[4][7];
#pragma unroll
  for (int a=0;a<4;++a)
#pragma unroll
    for (int q=0;q<7;++q){ bv[a][q]=-3.4e38f; bj[a][q]=-1; }

  for (int j0=0; j0<NN; j0+=512){
    __syncthreads();
    wj[t] = w[j0+t]; wj[256+t] = w[j0+256+t];
    float acc[4][8];
#pragma unroll
    for (int a=0;a<4;++a)
#pragma unroll
      for (int c=0;c<8;++c) acc[a][c]=0.f;
    for (int kc=0; kc<100; kc+=20){
      __syncthreads();
      {
        const float4* s0 = (const float4*)&S[(size_t)(j0+t)*CD + kc];
        const float4* s1 = (const float4*)&S[(size_t)(j0+256+t)*CD + kc];
        float4 u0=s0[0],u1=s0[1],u2=s0[2],u3=s0[3],u4=s0[4];
        float4 x0=s1[0],x1=s1[1],x2=s1[2],x3=s1[3],x4=s1[4];
        float* d0 = &Sj[t][0];
        d0[0]=u0.x; d0[1]=u0.y; d0[2]=u0.z; d0[3]=u0.w;
        d0[4]=u1.x; d0[5]=u1.y; d0[6]=u1.z; d0[7]=u1.w;
        d0[8]=u2.x; d0[9]=u2.y; d0[10]=u2.z; d0[11]=u2.w;
        d0[12]=u3.x; d0[13]=u3.y; d0[14]=u3.z; d0[15]=u3.w;
        d0[16]=u4.x; d0[17]=u4.y; d0[18]=u4.z; d0[19]=u4.w;
        float* d1 = &Sj[256+t][0];
        d1[0]=x0.x; d1[1]=x0.y; d1[2]=x0.z; d1[3]=x0.w;
        d1[4]=x1.x; d1[5]=x1.y; d1[6]=x1.z; d1[7]=x1.w;
        d1[8]=x2.x; d1[9]=x2.y; d1[10]=x2.z; d1[11]=x2.w;
        d1[12]=x3.x; d1[13]=x3.y; d1[14]=x3.z; d1[15]=x3.w;
        d1[16]=x4.x; d1[17]=x4.y; d1[18]=x4.z; d1[19]=x4.w;
      }
      __syncthreads();
#pragma unroll 4
      for (int k=0;k<20;++k){
        float a0=Si[rg*4+0][kc+k], a1=Si[rg*4+1][kc+k];
        float a2=Si[rg*4+2][kc+k], a3=Si[rg*4+3][kc+k];
#pragma unroll
        for (int c=0;c<8;++c){
          float b = Sj[c*64+ct][k];
          acc[0][c] += a0*b; acc[1][c] += a1*b;
          acc[2][c] += a2*b; acc[3][c] += a3*b;
        }
      }
    }
#pragma unroll
    for (int a=0;a<4;++a){
      const int i = i0 + rg*4 + a;
      const float wia = wi[rg*4+a];
#pragma unroll
      for (int c=0;c<8;++c){
        int j = j0 + c*64 + ct;
        float cv = acc[a][c] / fmaxf(wia*wj[c*64+ct], 1e-7f);
        cv = (j==i) ? -3.4e38f : cv;
        if (cv > bv[a][6]) ins7(bv[a], bj[a], cv, j);
      }
    }
  }
  // per-wave merge of 64 lanes' heaps, 4 rows per wave
#pragma unroll
  for (int a=0;a<4;++a){
    const int i = i0 + rg*4 + a;
    if (ct==0) idx[(size_t)i*8] = i;
    for (int rd=0; rd<7; ++rd){
      float v = bv[a][0]; int jv = bj[a][0]; int who = ct;
#pragma unroll
      for (int off=32; off; off>>=1){
        float ov = __shfl_down(v, off);
        int oj = __shfl_down(jv, off);
        int ow = __shfl_down(who, off);
        if (ov > v){ v=ov; jv=oj; who=ow; }
      }
      int jw = __shfl(jv, 0), ww = __shfl(who, 0);
      if (ct==0) idx[(size_t)i*8 + 1 + rd] = jw;
      if (ct==ww){
#pragma unroll
        for (int q=0;q<6;++q){ bv[a][q]=bv[a][q+1]; bj[a][q]=bj[a][q+1]; }
        bv[a][6]=-3.4e38f;
      }
    }
  }
}

// ---------- encoder: outb = bf16(l2norm(concat(h, mean(h[idx])) @ W + b)) ----------
__global__ __launch_bounds__(128) void encoder_kernel(const float* __restrict__ h,
                                                      const int* __restrict__ idx,
                                                      const float* __restrict__ W,
                                                      const float* __restrict__ bias,
                                                      unsigned short* __restrict__ outb)
{
  __shared__ float hin[256];
  __shared__ float sred[2];
  int i = blockIdx.x, t = threadIdx.x;
  float hv = h[(size_t)i*FF + t];
  float agg = 0.f;
#pragma unroll
  for (int m=0;m<8;++m) agg += h[(size_t)idx[i*8+m]*FF + t];
  agg *= 0.125f;
  hin[t] = hv; hin[FF + t] = agg;
  __syncthreads();
  float acc = bias[t];
  for (int k=0;k<256;++k) acc += hin[k] * W[(size_t)k*FF + t];
  float s = waveSum(acc*acc);
  int lane = t & 63, wid = t >> 6;
  if (lane==0) sred[wid]=s;
  __syncthreads();
  float tot = sred[0]+sred[1];
  outb[(size_t)i*FF + t] = f2bf(acc / sqrtf(tot));
}

// ---------- MFMA: C bf16 = A bf16 @ B^T, fused row-max/global-min stats ----------
__global__ __launch_bounds__(256) void gemm_btb_mfma(const unsigned short* __restrict__ A,
                                                     const unsigned short* __restrict__ B,
                                                     unsigned short* __restrict__ C,
                                                     uint* __restrict__ rmaxU,
                                                     uint* __restrict__ gminU)
{
  __shared__ unsigned short Al[64][136];
  __shared__ unsigned short Bl[64][136];
  const int tid = threadIdx.x;
  const int i0 = blockIdx.y*64, j0 = blockIdx.x*64;
#pragma unroll
  for (int it=0; it<4; ++it){
    int f = tid + it*256;
    int r = f >> 4, c8 = f & 15;
    *(uint4*)&Al[r][c8*8] = *(const uint4*)&A[(size_t)(i0+r)*FF + c8*8];
    *(uint4*)&Bl[r][c8*8] = *(const uint4*)&B[(size_t)(j0+r)*FF + c8*8];
  }
  __syncthreads();
  const int w = tid>>6, l = tid&63;
  const int wr = w>>1, wc = w&1;
  const int lrow = l&15, lk = (l>>4)*8;
  f32x4 acc[2][2];
#pragma unroll
  for (int mi=0;mi<2;++mi)
#pragma unroll
    for (int ni=0;ni<2;++ni) acc[mi][ni] = (f32x4){0.f,0.f,0.f,0.f};
#pragma unroll
  for (int ks=0; ks<4; ++ks){
    bf16x8 af[2], bfm[2];
#pragma unroll
    for (int mi=0;mi<2;++mi) af[mi] = *(bf16x8*)&Al[wr*32+mi*16+lrow][ks*32+lk];
#pragma unroll
    for (int ni=0;ni<2;++ni) bfm[ni] = *(bf16x8*)&Bl[wc*32+ni*16+lrow][ks*32+lk];
#pragma unroll
    for (int mi=0;mi<2;++mi)
#pragma unroll
      for (int ni=0;ni<2;++ni)
        acc[mi][ni] = __builtin_amdgcn_mfma_f32_16x16x32_bf16(af[mi], bfm[ni], acc[mi][ni], 0,0,0);
  }
  // fused stats (fp32 accuracy, pre-bf16)
  {
    float rmx[8]; float gmn = 3.4e38f;
#pragma unroll
    for (int mi=0;mi<2;++mi)
#pragma unroll
      for (int r=0;r<4;++r){
        float a = fmaxf(acc[mi][0][r], acc[mi][1][r]);
        float c = fminf(acc[mi][0][r], acc[mi][1][r]);
        rmx[mi*4+r] = a;
        gmn = fminf(gmn, c);
      }
#pragma unroll
    for (int mo=1;mo<16;mo<<=1){
#pragma unroll
      for (int q=0;q<8;++q) rmx[q] = fmaxf(rmx[q], __shfl_xor(rmx[q], mo));
      gmn = fminf(gmn, __shfl_xor(gmn, mo));
    }
    if ((l & 15) == 0){
#pragma unroll
      for (int mi=0;mi<2;++mi)
#pragma unroll
        for (int r=0;r<4;++r){
          int row = i0 + wr*32 + mi*16 + (l>>4)*4 + r;
          atomicMax(&rmaxU[row], fkey(rmx[mi*4+r]));
        }
      atomicMin(gminU, fkey(gmn));
    }
  }
  __syncthreads();
  unsigned short (*Cl)[72] = (unsigned short(*)[72])&Al[0][0];
#pragma unroll
  for (int mi=0;mi<2;++mi)
#pragma unroll
    for (int ni=0;ni<2;++ni)
#pragma unroll
      for (int r=0;r<4;++r){
        int row = wr*32 + mi*16 + (l>>4)*4 + r;
        int col = wc*32 + ni*16 + lrow;
        Cl[row][col] = f2bf(acc[mi][ni][r]);
      }
  __syncthreads();
#pragma unroll
  for (int it=0; it<2; ++it){
    int f = tid + it*256;
    int r = f >> 3, c8 = f & 7;
    *(uint4*)&C[(size_t)(i0+r)*NN + j0 + c8*8] = *(uint4*)&Cl[r][c8*8];
  }
}

// ---------- per-batch init: v=1, stats keys ----------
__global__ void stats_init(float* __restrict__ v, uint* __restrict__ rmaxU,
                           uint* __restrict__ gminU, int nmat)
{
  int g = blockIdx.x*256 + threadIdx.x;
  if (g < nmat*NN){ v[g] = 1.f; rmaxU[g] = 0u; }
  if (g < nmat) gminU[g] = 0xFFFFFFFFu;
}

// ---------- stat finalize: stat[m] = {gmin, 1/(gmax-gmin)} ----------
__global__ __launch_bounds__(256) void greduce2(const uint* __restrict__ rmaxU,
                                                const uint* __restrict__ gminU,
                                                float* __restrict__ stat)
{
  __shared__ float red[4];
  int m = blockIdx.x, t = threadIdx.x;
  float mx = -3.4e38f;
  for (int i=t;i<NN;i+=256) mx = fmaxf(mx, fdec(rmaxU[(size_t)m*NN+i]));
  float gmx = blkMax(mx, red);
  if (t==0){
    float gmn = fdec(gminU[m]);
    stat[m*2]   = gmn;
    stat[m*2+1] = 1.f/(gmx-gmn);
  }
}

// ---------- K8 = fp8(exp((M0 - rowmax)*scale)); M output for finalm ----------
__global__ __launch_bounds__(256) void transform_b(const unsigned short* __restrict__ Kbase,
                                                   uchar* __restrict__ K8base,
                                                   const uint* __restrict__ rmaxU,
                                                   const float* __restrict__ stat,
                                                   float* __restrict__ Mout, int finalm)
{
  int m = blockIdx.y;
  const float gmin = stat[m*2], scale = stat[m*2+1];
  const uint4* Km = (const uint4*)(Kbase + (size_t)m*NN*NN);
  uint2* K8 = (uint2*)(K8base + (size_t)m*NN*NN);
  const bool wM = (m==finalm) && (Mout != nullptr);
  const int total8 = (NN*NN)/8;
  for (int f = blockIdx.x*256 + threadIdx.x; f < total8; f += 256*256){
    int i = f >> 9;
    float rm = fdec(rmaxU[(size_t)m*NN + i]);
    float e[8]; unpack8(Km[f], e);
    float kx[8];
#pragma unroll
    for (int k=0;k<8;++k) kx[k] = __expf((e[k]-rm)*scale);
    uint2 o;
    o.x = e8(kx[0]) | (e8(kx[1])<<8) | (e8(kx[2])<<16) | (e8(kx[3])<<24);
    o.y = e8(kx[4]) | (e8(kx[5])<<8) | (e8(kx[6])<<16) | (e8(kx[7])<<24);
    K8[f] = o;
    if (wM){
      float4 o1, o2;
      o1.x=(e[0]-gmin)*scale; o1.y=(e[1]-gmin)*scale; o1.z=(e[2]-gmin)*scale; o1.w=(e[3]-gmin)*scale;
      o2.x=(e[4]-gmin)*scale; o2.y=(e[5]-gmin)*scale; o2.z=(e[6]-gmin)*scale; o2.w=(e[7]-gmin)*scale;
      float4* mp = (float4*)(Mout + (size_t)f*8);
      mp[0]=o1; mp[1]=o2;
    }
  }
}

// ---------- fused sinkhorn iteration over fp8 K: one pass, row+col ----------
__global__ __launch_bounds__(256) void sink_fused(const uchar* __restrict__ K8base,
                                                  const float* __restrict__ vv,
                                                  unsigned short* __restrict__ part)
{
  __shared__ float red[4];
  const int m = blockIdx.y, b = blockIdx.x, t = threadIdx.x;
  const int i0 = b*CHUNK;
  const uchar* K8 = K8base + (size_t)m*NN*NN;
  const float4* v4 = (const float4*)(vv + (size_t)m*NN);
  float vs[16];
  {
    float4 A=v4[t*4+0], B=v4[t*4+1], C=v4[t*4+2], D=v4[t*4+3];
    vs[0]=A.x; vs[1]=A.y; vs[2]=A.z; vs[3]=A.w;
    vs[4]=B.x; vs[5]=B.y; vs[6]=B.z; vs[7]=B.w;
    vs[8]=C.x; vs[9]=C.y; vs[10]=C.z; vs[11]=C.w;
    vs[12]=D.x; vs[13]=D.y; vs[14]=D.z; vs[15]=D.w;
  }
  float colacc[16];
#pragma unroll
  for (int k=0;k<16;++k) colacc[k]=0.f;
  for (int r=0;r<CHUNK;++r){
    uint4 kw = ((const uint4*)(K8 + (size_t)(i0+r)*NN))[t];
    float e[16];
    d8x4(kw.x, e); d8x4(kw.y, e+4); d8x4(kw.z, e+8); d8x4(kw.w, e+12);
    float dot = 0.f;
#pragma unroll
    for (int k=0;k<16;++k) dot += e[k]*vs[k];
    float rowsum = blkSum(dot, red);
    float ur = RVAL / rowsum;
#pragma unroll
    for (int k=0;k<16;++k) colacc[k] += e[k]*ur;
  }
  unsigned short* prow = part + ((size_t)m*NCH + b)*NN;
  ((uint4*)prow)[t*2]   = pack8(colacc);
  ((uint4*)prow)[t*2+1] = pack8(colacc+8);
}

// ---------- column finish: v[j] = R / sum_b part[m][b][j] ----------
__global__ __launch_bounds__(256) void colfin_b(const unsigned short* __restrict__ part,
                                                float* __restrict__ vv)
{
  __shared__ float lds[16][16][8];
  const int m = blockIdx.y, bx = blockIdx.x, t = threadIdx.x;
  const int g = t & 15;
  const int tq = t >> 4;
  const uint4* pb = (const uint4*)(part + (size_t)m*NCH*NN);
  float acc[8];
#pragma unroll
  for (int k=0;k<8;++k) acc[k]=0.f;
#pragma unroll 4
  for (int s=0;s<8;++s){
    int b = tq + s*16;
    float e[8]; unpack8(pb[(size_t)b*512 + bx*16 + g], e);
#pragma unroll
    for (int k=0;k<8;++k) acc[k] += e[k];
  }
#pragma unroll
  for (int k=0;k<8;++k) lds[tq][g][k] = acc[k];
  __syncthreads();
  if (t < 128){
    int gg = t >> 3, c = t & 7;
    float s = 0.f;
#pragma unroll
    for (int q=0;q<16;++q) s += lds[q][gg][c];
    vv[(size_t)m*NN + bx*128 + gg*8 + c] = RVAL / s;
  }
}

// ---------- final: y = Kv ; P = K v_j / y ; per-row loss partial ----------
__global__ __launch_bounds__(256) void loss2_b(const uchar* __restrict__ K8base,
                                               const float* __restrict__ vv,
                                               float* __restrict__ accf,
                                               float* __restrict__ Pout, int finalm)
{
  __shared__ float red[4];
  int m = blockIdx.y, i = blockIdx.x, t = threadIdx.x;
  const uint4* row = (const uint4*)(K8base + ((size_t)m*NN + i)*NN);
  const float4* v4 = (const float4*)(vv + (size_t)m*NN);
  uint4 kw = row[t];
  float e[16];
  d8x4(kw.x, e); d8x4(kw.y, e+4); d8x4(kw.z, e+8); d8x4(kw.w, e+12);
  float vr[16];
  {
    float4 A=v4[t*4+0], B=v4[t*4+1], C=v4[t*4+2], D=v4[t*4+3];
    vr[0]=A.x; vr[1]=A.y; vr[2]=A.z; vr[3]=A.w;
    vr[4]=B.x; vr[5]=B.y; vr[6]=B.z; vr[7]=B.w;
    vr[8]=C.x; vr[9]=C.y; vr[10]=C.z; vr[11]=C.w;
    vr[12]=D.x; vr[13]=D.y; vr[14]=D.z; vr[15]=D.w;
  }
  float s = 0.f;
#pragma unroll
  for (int k=0;k<16;++k) s += e[k]*vr[k];
  float y = blkSum(s, red);
  float invy = 1.f / y;
  const bool wp = (m==finalm) && (Pout != nullptr);
  const int j0 = t*16;
  float p[16];
#pragma unroll
  for (int k=0;k<16;++k) p[k] = e[k]*vr[k]*invy;
  if (wp){
    float4* pp = (float4*)(Pout + (size_t)i*NN + j0);
#pragma unroll
    for (int q=0;q<4;++q){
      float4 o; o.x=p[q*4]; o.y=p[q*4+1]; o.z=p[q*4+2]; o.w=p[q*4+3];
      pp[q]=o;
    }
  }
  float local = 0.f;
#pragma unroll
  for (int k=0;k<16;++k){
    float d = p[k] - ((j0+k)==i ? 1.f : 0.f);
    local += d*d;
  }
  float tot = blkSum(local, red);
  if (t==0) accf[(size_t)m*NN + i] = tot;
}

// ---------- deterministic loss reduce: out = sqrt(sum accf) ----------
__global__ __launch_bounds__(256) void lossfin2(const float* __restrict__ accf,
                                                float* __restrict__ outslot)
{
  __shared__ float red[4];
  int t = threadIdx.x;
  float s = 0.f;
#pragma unroll
  for (int q=0;q<16;++q) s += accf[t + q*256];
  float tot = blkSum(s, red);
  if (t==0) *outslot = sqrtf(tot);
}

__global__ void sumloss(float* __restrict__ out)
{
  if (threadIdx.x==0) out[0] = out[1]+out[2]+out[3]+out[4];
}

extern "C" void kernel_launch(void* const* d_in, const int* in_sizes, int n_in,
                              void* d_out, int out_size, void* d_ws, size_t ws_size,
                              hipStream_t stream)
{
  (void)in_sizes; (void)n_in; (void)out_size;
  const float* f_s  = (const float*)d_in[1];
  const float* l_s  = (const float*)d_in[2];
  const float* f_t  = (const float*)d_in[3];
  const float* l_t  = (const float*)d_in[4];
  const float* W_es = (const float*)d_in[5];
  const float* b_es = (const float*)d_in[6];
  const float* W_et = (const float*)d_in[7];
  const float* b_et = (const float*)d_in[8];
  const float* W_gs = (const float*)d_in[9];
  const float* b_gs = (const float*)d_in[10];
  const float* W_gt = (const float*)d_in[11];
  const float* b_gt = (const float*)d_in[12];
  float* out = (float*)d_out;

  char* ws = (char*)d_ws;
  size_t off = 0;
  auto alloc = [&](size_t nbytes)->void*{
    off = (off + 255) & ~(size_t)255;
    void* p = ws + off; off += nbytes; return p;
  };
  float* f_es = (float*)alloc((size_t)NN*FF*4);
  float* f_et = (float*)alloc((size_t)NN*FF*4);
  unsigned short* f_esb = (unsigned short*)alloc((size_t)NN*FF*2);
  unsigned short* f_etb = (unsigned short*)alloc((size_t)NN*FF*2);
  unsigned short* f_gsb = (unsigned short*)alloc((size_t)NN*FF*2);
  unsigned short* f_gtb = (unsigned short*)alloc((size_t)NN*FF*2);
  float* S_s  = (float*)alloc((size_t)NN*CD*4);
  float* S_t  = (float*)alloc((size_t)NN*CD*4);
  float* w_s  = (float*)alloc(NN*4);
  float* w_t  = (float*)alloc(NN*4);
  int*   idx_s= (int*)alloc(NN*8*4);
  int*   idx_t= (int*)alloc(NN*8*4);
  uint*  rmaxU= (uint*)alloc((size_t)4*NN*4);
  uint*  gminU= (uint*)alloc(64);
  float* stat = (float*)alloc(64);
  float* v    = (float*)alloc((size_t)4*NN*4);
  float* accf = (float*)alloc((size_t)4*NN*4);
  unsigned short* part = (unsigned short*)alloc((size_t)4*NCH*NN*2);
  off = (off + 255) & ~(size_t)255;
  unsigned short* Kb = (unsigned short*)(ws + off);
  size_t remain = (ws_size > off) ? ws_size - off : 0;
  const size_t matB  = (size_t)NN*NN*2;   // bf16 M0
  const size_t mat8B = (size_t)NN*NN;     // fp8 K
  int nb;
  if      (remain >= 4*(matB+mat8B)) nb = 4;
  else if (remain >= 2*(matB+mat8B)) nb = 2;
  else                               nb = 1;
  uchar* K8 = (uchar*)(Kb + (size_t)nb*NN*NN);

  // embed scratch aliases the Kb region (used strictly before OT)
  float* epart = (float*)Kb;                                    // KS*NN*FF*4 = 32MB
  unsigned short* Wt0 = (unsigned short*)((char*)Kb + (size_t)KS*NN*FF*4);
  unsigned short* Wt1 = Wt0 + (size_t)FF*EK;

  float* Pout_final = out + 5;
  float* Mout_final = out + 5 + (size_t)NN*NN;

  // ---- embeddings (MFMA split-K) ----
  transposeW<<<EK/64,256,0,stream>>>(W_es, Wt0);
  transposeW<<<EK/64,256,0,stream>>>(W_et, Wt1);
  embed_mfma<<<dim3(64,KS),256,0,stream>>>(f_s, Wt0, epart);
  reduce_l2<<<NN,128,0,stream>>>(epart, b_es, f_es, f_esb);
  embed_mfma<<<dim3(64,KS),256,0,stream>>>(f_t, Wt1, epart);
  reduce_l2<<<NN,128,0,stream>>>(epart, b_et, f_et, f_etb);

  // ---- knn path (fused, no D matrix) ----
  softmax_rows<<<NN,128,0,stream>>>(l_s, S_s, w_s);
  softmax_rows<<<NN,128,0,stream>>>(l_t, S_t, w_t);
  knn_fused<<<NN/16,256,0,stream>>>(S_s, w_s, idx_s);
  knn_fused<<<NN/16,256,0,stream>>>(S_t, w_t, idx_t);
  encoder_kernel<<<NN,128,0,stream>>>(f_es, idx_s, W_gs, b_gs, f_gsb);
  encoder_kernel<<<NN,128,0,stream>>>(f_et, idx_t, W_gt, b_gt, f_gtb);

  // ---- batched OT ----
  const unsigned short* ftab[4] = { f_etb, f_gtb, f_etb, f_gtb };
  const unsigned short* fsab[4] = { f_esb, f_esb, f_gtb, f_gsb };
  const int slotab[4]  = { 1, 3, 4, 2 };

  auto run_batch = [&](int m0, int nmat, int finalm){
    stats_init<<<(4*NN+255)/256,256,0,stream>>>(v, rmaxU, gminU, nmat);
    for (int m=0;m<nmat;++m)
      gemm_btb_mfma<<<dim3(64,64),256,0,stream>>>(ftab[m0+m], fsab[m0+m],
          Kb + (size_t)m*NN*NN, rmaxU + (size_t)m*NN, gminU + m);
    greduce2<<<nmat,256,0,stream>>>(rmaxU, gminU, stat);
    transform_b<<<dim3(256,nmat),256,0,stream>>>(Kb, K8, rmaxU, stat,
        (finalm>=0)?Mout_final:(float*)nullptr, finalm);
    for (int it=0; it<OT_ITERS; ++it){
      sink_fused<<<dim3(NCH,nmat),256,0,stream>>>(K8, v, part);
      colfin_b<<<dim3(32,nmat),256,0,stream>>>(part, v);
    }
    loss2_b<<<dim3(NN,nmat),256,0,stream>>>(K8, v, accf,
        (finalm>=0)?Pout_final:(float*)nullptr, finalm);
    for (int m=0;m<nmat;++m)
      lossfin2<<<1,256,0,stream>>>(accf + (size_t)m*NN, out + slotab[m0+m]);
  };

  for (int m0=0; m0<4; m0+=nb){
    int nmat = (4-m0 < nb) ? (4-m0) : nb;
    int finalm = (3>=m0 && 3<m0+nmat) ? (3-m0) : -1;
    run_batch(m0, nmat, finalm);
  }

  sumloss<<<1,1,0,stream>>>(out);
}

// Round 7
// 1852.721 us; speedup vs baseline: 1.1124x; 1.1124x over previous
//
#include <hip/hip_runtime.h>
#include <math.h>

#define NN 4096
#define FF 128
#define CD 100
#define OT_ITERS 20
#define RVAL (1.0f/4096.0f)
#define EK 8192
#define KS 8
#define CHUNK 16
#define NCH 256

typedef unsigned int uint;
typedef unsigned char uchar;
typedef __attribute__((ext_vector_type(8))) short bf16x8;
typedef __attribute__((ext_vector_type(4))) float f32x4;

// ---------- bf16 helpers ----------
__device__ __forceinline__ float bflo(uint u){ return __uint_as_float(u << 16); }
__device__ __forceinline__ float bfhi(uint u){ return __uint_as_float(u & 0xFFFF0000u); }
__device__ __forceinline__ unsigned short f2bf(float x){
  uint u = __float_as_uint(x);
  u += 0x7FFFu + ((u >> 16) & 1u);
  return (unsigned short)(u >> 16);
}
__device__ __forceinline__ void unpack8(uint4 kk, float* e){
  e[0]=bflo(kk.x); e[1]=bfhi(kk.x); e[2]=bflo(kk.y); e[3]=bfhi(kk.y);
  e[4]=bflo(kk.z); e[5]=bfhi(kk.z); e[6]=bflo(kk.w); e[7]=bfhi(kk.w);
}
__device__ __forceinline__ uint4 pack8(const float* e){
  union { unsigned short us[8]; uint4 u4; } pk;
#pragma unroll
  for (int k=0;k<8;++k) pk.us[k]=f2bf(e[k]);
  return pk.u4;
}

// ---------- ordered-float key encoding for atomic min/max ----------
__device__ __forceinline__ uint fkey(float f){
  uint u = __float_as_uint(f);
  return (u & 0x80000000u) ? ~u : (u | 0x80000000u);
}
__device__ __forceinline__ float fdec(uint k){
  uint u = (k & 0x80000000u) ? (k & 0x7FFFFFFFu) : ~k;
  return __uint_as_float(u);
}

// ---------- fp8 e4m3-style codec (domain K in [1/e, 1], always normal) ----------
__device__ __forceinline__ uint e8(float f){
  uint u = __float_as_uint(f);
  uint m23 = u & 0x7FFFFFu;
  uint rnd = 0x7FFFFu + ((m23 >> 20) & 1u);
  uint mr  = m23 + rnd;
  uint e   = (u >> 23) & 0xFFu;
  uint m3  = (mr >> 20) & 7u;
  e += (mr >> 23);
  return (((e - 120u) << 3) | m3) & 0x7Fu;
}
__device__ __forceinline__ void d8x4(uint w, float* e){
  e[0]=__uint_as_float((( w      & 0x7Fu)<<20)+0x3C000000u);
  e[1]=__uint_as_float((((w>> 8) & 0x7Fu)<<20)+0x3C000000u);
  e[2]=__uint_as_float((((w>>16) & 0x7Fu)<<20)+0x3C000000u);
  e[3]=__uint_as_float((((w>>24) & 0x7Fu)<<20)+0x3C000000u);
}

// ---------- wave/block reduce helpers (wave = 64) ----------
__device__ __forceinline__ float waveSum(float v){
#pragma unroll
  for (int o=32;o>0;o>>=1) v += __shfl_down(v,o);
  return v;
}
__device__ __forceinline__ float waveMax(float v){
#pragma unroll
  for (int o=32;o>0;o>>=1) v = fmaxf(v,__shfl_down(v,o));
  return v;
}
__device__ __forceinline__ float blkSum(float v, float* red){
  v = waveSum(v);
  if ((threadIdx.x&63)==0) red[threadIdx.x>>6] = v;
  __syncthreads();
  float r = red[0]+red[1]+red[2]+red[3];
  __syncthreads();
  return r;
}
__device__ __forceinline__ float blkMax(float v, float* red){
  v = waveMax(v);
  if ((threadIdx.x&63)==0) red[threadIdx.x>>6] = v;
  __syncthreads();
  float r = fmaxf(fmaxf(red[0],red[1]),fmaxf(red[2],red[3]));
  __syncthreads();
  return r;
}

// ---------- W transpose+convert: Wt[n][k] bf16 from W[k][n] fp32 ----------
__global__ __launch_bounds__(256) void transposeW(const float* __restrict__ W,
                                                  unsigned short* __restrict__ Wt)
{
  __shared__ unsigned short T[128][72];
  const int k0 = blockIdx.x*64, tid = threadIdx.x;
#pragma unroll
  for (int it=0; it<8; ++it){
    int f = tid + it*256;
    int r = f >> 5, c4 = f & 31;
    float4 v = *(const float4*)&W[(size_t)(k0+r)*FF + c4*4];
    T[c4*4+0][r]=f2bf(v.x); T[c4*4+1][r]=f2bf(v.y);
    T[c4*4+2][r]=f2bf(v.z); T[c4*4+3][r]=f2bf(v.w);
  }
  __syncthreads();
#pragma unroll
  for (int it=0; it<4; ++it){
    int f = tid + it*256;
    int n = f >> 3, c8 = f & 7;
    *(uint4*)&Wt[(size_t)n*EK + k0 + c8*8] = *(uint4*)&T[n][c8*8];
  }
}

// ---------- MFMA embed GEMM (split-K=8): part[ks][4096][128] ----------
__global__ __launch_bounds__(256) void embed_mfma(const float* __restrict__ A,
                                                  const unsigned short* __restrict__ Wt,
                                                  float* __restrict__ part)
{
  __shared__ unsigned short Al[64][72];
  __shared__ unsigned short Wl[128][72];
  const int tid = threadIdx.x;
  const int m0 = blockIdx.x * 64;
  const int kc = blockIdx.y * (EK/KS);
  const int w = tid >> 6, l = tid & 63;
  const int wr = w >> 1, wc = w & 1;
  const int lrow = l & 15, lk = (l >> 4) * 8;
  f32x4 acc[2][4];
#pragma unroll
  for (int mi=0;mi<2;++mi)
#pragma unroll
    for (int ni=0;ni<4;++ni) acc[mi][ni] = (f32x4){0.f,0.f,0.f,0.f};

  for (int k0 = kc; k0 < kc + EK/KS; k0 += 64) {
#pragma unroll
    for (int it = 0; it < 4; ++it) {
      int f = tid + it*256;
      int r = f >> 4, c4 = f & 15;
      float4 a4 = *(const float4*)&A[(size_t)(m0+r)*EK + k0 + c4*4];
      union { unsigned short us[4]; uint2 u2; } pk;
      pk.us[0]=f2bf(a4.x); pk.us[1]=f2bf(a4.y); pk.us[2]=f2bf(a4.z); pk.us[3]=f2bf(a4.w);
      *(uint2*)&Al[r][c4*4] = pk.u2;
    }
#pragma unroll
    for (int it = 0; it < 4; ++it) {
      int f = tid + it*256;
      int r = f >> 3, c8 = f & 7;
      *(uint4*)&Wl[r][c8*8] = *(const uint4*)&Wt[(size_t)r*EK + k0 + c8*8];
    }
    __syncthreads();
#pragma unroll
    for (int ksub = 0; ksub < 2; ++ksub) {
      bf16x8 af[2], bfr[4];
#pragma unroll
      for (int mi=0;mi<2;++mi) af[mi] = *(bf16x8*)&Al[wr*32+mi*16+lrow][ksub*32+lk];
#pragma unroll
      for (int ni=0;ni<4;++ni) bfr[ni] = *(bf16x8*)&Wl[wc*64+ni*16+lrow][ksub*32+lk];
#pragma unroll
      for (int mi=0;mi<2;++mi)
#pragma unroll
        for (int ni=0;ni<4;++ni)
          acc[mi][ni] = __builtin_amdgcn_mfma_f32_16x16x32_bf16(af[mi], bfr[ni], acc[mi][ni], 0,0,0);
    }
    __syncthreads();
  }
#pragma unroll
  for (int mi=0;mi<2;++mi)
#pragma unroll
    for (int ni=0;ni<4;++ni)
#pragma unroll
      for (int r=0;r<4;++r) {
        int row = m0 + wr*32 + mi*16 + (l>>4)*4 + r;
        int col = wc*64 + ni*16 + lrow;
        part[((size_t)blockIdx.y*NN + row)*FF + col] = acc[mi][ni][r];
      }
}

// ---------- reduce split-K partials + bias + l2norm -> fp32 and bf16 ----------
__global__ __launch_bounds__(128) void reduce_l2(const float* __restrict__ part,
                                                 const float* __restrict__ bias,
                                                 float* __restrict__ out,
                                                 unsigned short* __restrict__ outb)
{
  __shared__ float red[2];
  int i = blockIdx.x, t = threadIdx.x;
  float s = bias[t];
#pragma unroll
  for (int ks=0; ks<KS; ++ks) s += part[((size_t)ks*NN + i)*FF + t];
  float q = waveSum(s*s);
  if ((t&63)==0) red[t>>6]=q;
  __syncthreads();
  float val = s / sqrtf(red[0]+red[1]);
  out[(size_t)i*FF+t] = val;
  outb[(size_t)i*FF+t] = f2bf(val);
}

// ---------- softmax rows of l[4096x100] -> S, w = ||S_row|| ----------
__global__ __launch_bounds__(128) void softmax_rows(const float* __restrict__ l,
                                                    float* __restrict__ S,
                                                    float* __restrict__ w)
{
  __shared__ float sm[2], ss[2], sq[2];
  int i = blockIdx.x, t = threadIdx.x;
  int lane = t & 63, wid = t >> 6;
  float x = (t < CD) ? l[(size_t)i*CD + t] : -3.4e38f;
  float m = waveMax(x);
  if (lane==0) sm[wid]=m;
  __syncthreads();
  m = fmaxf(sm[0], sm[1]);
  float e = (t < CD) ? __expf(x - m) : 0.f;
  float s = waveSum(e);
  if (lane==0) ss[wid]=s;
  __syncthreads();
  float tot = ss[0]+ss[1];
  float sv = e / tot;
  if (t < CD) S[(size_t)i*CD + t] = sv;
  float q = waveSum(sv*sv);
  if (lane==0) sq[wid]=q;
  __syncthreads();
  if (t==0) w[i] = sqrtf(sq[0]+sq[1]);
}

// ---------- cos matrix: D[i][j] = (S_i . S_j)/max(w_i w_j, eps), diag = -2 ----------
__global__ __launch_bounds__(256) void cos_gemm(const float* __restrict__ S,
                                                const float* __restrict__ w,
                                                float* __restrict__ D)
{
  __shared__ float As[64][108];
  __shared__ float Bs[100][68];
  const int tid = threadIdx.x;
  const int tc = tid & 15, tr = tid >> 4;
  const int i0 = blockIdx.y*64, j0 = blockIdx.x*64;
  for (int f = tid; f < 64*25; f += 256){
    int r = f/25, c4 = f%25;
    *(float4*)&As[r][c4*4] = *(const float4*)&S[(size_t)(i0+r)*CD + c4*4];
  }
  for (int f = tid; f < 64*25; f += 256){
    int r = f/25, c4 = f%25;
    float4 bv = *(const float4*)&S[(size_t)(j0+r)*CD + c4*4];
    Bs[c4*4+0][r]=bv.x; Bs[c4*4+1][r]=bv.y; Bs[c4*4+2][r]=bv.z; Bs[c4*4+3][r]=bv.w;
  }
  __syncthreads();
  float acc[4][4];
#pragma unroll
  for (int a=0;a<4;++a)
#pragma unroll
    for (int b=0;b<4;++b) acc[a][b]=0.f;
  for (int kk=0; kk<100; kk+=4){
    float a[4][4];
#pragma unroll
    for (int q=0;q<4;++q) *(float4*)a[q] = *(const float4*)&As[tr*4+q][kk];
#pragma unroll
    for (int t4=0;t4<4;++t4){
      float4 b = *(const float4*)&Bs[kk+t4][tc*4];
#pragma unroll
      for (int rr=0;rr<4;++rr){
        float av = a[rr][t4];
        acc[rr][0] += av*b.x; acc[rr][1] += av*b.y;
        acc[rr][2] += av*b.z; acc[rr][3] += av*b.w;
      }
    }
  }
  float wi[4], wj[4];
#pragma unroll
  for (int q=0;q<4;++q){ wi[q] = w[i0+tr*4+q]; wj[q] = w[j0+tc*4+q]; }
#pragma unroll
  for (int rr=0;rr<4;++rr){
    int i = i0+tr*4+rr;
    float4 o;
    float* op = (float*)&o;
#pragma unroll
    for (int cc=0;cc<4;++cc){
      int j = j0+tc*4+cc;
      float val = acc[rr][cc] / fmaxf(wi[rr]*wj[cc], 1e-7f);
      op[cc] = (i==j) ? -2.f : val;
    }
    *(float4*)&D[(size_t)i*NN + j0 + tc*4] = o;
  }
}

// ---------- top-7 select per row of D; idx[i][0] = i ----------
__global__ __launch_bounds__(256) void knn_select(const float* __restrict__ D,
                                                  int* __restrict__ idx)
{
  __shared__ float redv[256];
  __shared__ int   redi[256];
  int i = blockIdx.x, tid = threadIdx.x;
  float bv[7]; int bi[7];
#pragma unroll
  for (int m=0;m<7;++m){ bv[m]=-3.4e38f; bi[m]=-1; }
  const float4* row4 = (const float4*)&D[(size_t)i*NN];
#pragma unroll
  for (int s=0;s<4;++s){
    int j4 = tid + s*256;
    float4 vv = row4[j4];
    float cv[4] = {vv.x, vv.y, vv.z, vv.w};
#pragma unroll
    for (int q=0;q<4;++q){
      if (cv[q] > bv[6]) {
        int m = 6;
        while (m > 0 && cv[q] > bv[m-1]) { bv[m]=bv[m-1]; bi[m]=bi[m-1]; --m; }
        bv[m]=cv[q]; bi[m]=j4*4+q;
      }
    }
  }
  if (tid==0) idx[(size_t)i*8] = i;
  for (int m=0;m<7;++m) {
    redv[tid]=bv[0]; redi[tid]=tid;
    __syncthreads();
    for (int s=128;s>=1;s>>=1) {
      if (tid < s) {
        if (redv[tid+s] > redv[tid]) { redv[tid]=redv[tid+s]; redi[tid]=redi[tid+s]; }
      }
      __syncthreads();
    }
    int wt = redi[0];
    if (tid == wt) {
      idx[(size_t)i*8 + 1 + m] = bi[0];
#pragma unroll
      for (int q=0;q<6;++q){ bv[q]=bv[q+1]; bi[q]=bi[q+1]; }
      bv[6]=-3.4e38f; bi[6]=-1;
    }
    __syncthreads();
  }
}

// ---------- encoder: outb = bf16(l2norm(concat(h, mean(h[idx])) @ W + b)) ----------
__global__ __launch_bounds__(128) void encoder_kernel(const float* __restrict__ h,
                                                      const int* __restrict__ idx,
                                                      const float* __restrict__ W,
                                                      const float* __restrict__ bias,
                                                      unsigned short* __restrict__ outb)
{
  __shared__ float hin[256];
  __shared__ float sred[2];
  int i = blockIdx.x, t = threadIdx.x;
  float hv = h[(size_t)i*FF + t];
  float agg = 0.f;
#pragma unroll
  for (int m=0;m<8;++m) agg += h[(size_t)idx[i*8+m]*FF + t];
  agg *= 0.125f;
  hin[t] = hv; hin[FF + t] = agg;
  __syncthreads();
  float acc = bias[t];
  for (int k=0;k<256;++k) acc += hin[k] * W[(size_t)k*FF + t];
  float s = waveSum(acc*acc);
  int lane = t & 63, wid = t >> 6;
  if (lane==0) sred[wid]=s;
  __syncthreads();
  float tot = sred[0]+sred[1];
  outb[(size_t)i*FF + t] = f2bf(acc / sqrtf(tot));
}

// ---------- MFMA: stage bf16 = A bf16 @ B^T, fused row-max/global-min stats ----------
__global__ __launch_bounds__(256) void gemm_btb_mfma(const unsigned short* __restrict__ A,
                                                     const unsigned short* __restrict__ B,
                                                     unsigned short* __restrict__ C,
                                                     uint* __restrict__ rmaxU,
                                                     uint* __restrict__ gminU)
{
  __shared__ unsigned short Al[64][136];
  __shared__ unsigned short Bl[64][136];
  const int tid = threadIdx.x;
  const int i0 = blockIdx.y*64, j0 = blockIdx.x*64;
#pragma unroll
  for (int it=0; it<4; ++it){
    int f = tid + it*256;
    int r = f >> 4, c8 = f & 15;
    *(uint4*)&Al[r][c8*8] = *(const uint4*)&A[(size_t)(i0+r)*FF + c8*8];
    *(uint4*)&Bl[r][c8*8] = *(const uint4*)&B[(size_t)(j0+r)*FF + c8*8];
  }
  __syncthreads();
  const int w = tid>>6, l = tid&63;
  const int wr = w>>1, wc = w&1;
  const int lrow = l&15, lk = (l>>4)*8;
  f32x4 acc[2][2];
#pragma unroll
  for (int mi=0;mi<2;++mi)
#pragma unroll
    for (int ni=0;ni<2;++ni) acc[mi][ni] = (f32x4){0.f,0.f,0.f,0.f};
#pragma unroll
  for (int ks=0; ks<4; ++ks){
    bf16x8 af[2], bfm[2];
#pragma unroll
    for (int mi=0;mi<2;++mi) af[mi] = *(bf16x8*)&Al[wr*32+mi*16+lrow][ks*32+lk];
#pragma unroll
    for (int ni=0;ni<2;++ni) bfm[ni] = *(bf16x8*)&Bl[wc*32+ni*16+lrow][ks*32+lk];
#pragma unroll
    for (int mi=0;mi<2;++mi)
#pragma unroll
      for (int ni=0;ni<2;++ni)
        acc[mi][ni] = __builtin_amdgcn_mfma_f32_16x16x32_bf16(af[mi], bfm[ni], acc[mi][ni], 0,0,0);
  }
  // fused stats (fp32 accuracy, pre-bf16)
  {
    float rmx[8]; float gmn = 3.4e38f;
#pragma unroll
    for (int mi=0;mi<2;++mi)
#pragma unroll
      for (int r=0;r<4;++r){
        float a = fmaxf(acc[mi][0][r], acc[mi][1][r]);
        float c = fminf(acc[mi][0][r], acc[mi][1][r]);
        rmx[mi*4+r] = a;
        gmn = fminf(gmn, c);
      }
#pragma unroll
    for (int mo=1;mo<16;mo<<=1){
#pragma unroll
      for (int q=0;q<8;++q) rmx[q] = fmaxf(rmx[q], __shfl_xor(rmx[q], mo));
      gmn = fminf(gmn, __shfl_xor(gmn, mo));
    }
    if ((l & 15) == 0){
#pragma unroll
      for (int mi=0;mi<2;++mi)
#pragma unroll
        for (int r=0;r<4;++r){
          int row = i0 + wr*32 + mi*16 + (l>>4)*4 + r;
          atomicMax(&rmaxU[row], fkey(rmx[mi*4+r]));
        }
      atomicMin(gminU, fkey(gmn));
    }
  }
  __syncthreads();
  unsigned short (*Cl)[72] = (unsigned short(*)[72])&Al[0][0];
#pragma unroll
  for (int mi=0;mi<2;++mi)
#pragma unroll
    for (int ni=0;ni<2;++ni)
#pragma unroll
      for (int r=0;r<4;++r){
        int row = wr*32 + mi*16 + (l>>4)*4 + r;
        int col = wc*32 + ni*16 + lrow;
        Cl[row][col] = f2bf(acc[mi][ni][r]);
      }
  __syncthreads();
#pragma unroll
  for (int it=0; it<2; ++it){
    int f = tid + it*256;
    int r = f >> 3, c8 = f & 7;
    *(uint4*)&C[(size_t)(i0+r)*NN + j0 + c8*8] = *(uint4*)&Cl[r][c8*8];
  }
}

// ---------- init: v=1, stats keys (all 4 matrices) ----------
__global__ void stats_init(float* __restrict__ v, uint* __restrict__ rmaxU,
                           uint* __restrict__ gminU)
{
  int g = blockIdx.x*256 + threadIdx.x;
  if (g < 4*NN){ v[g] = 1.f; rmaxU[g] = 0u; }
  if (g < 4) gminU[g] = 0xFFFFFFFFu;
}

// ---------- stat finalize (single matrix): stat = {gmin, 1/(gmax-gmin)} ----------
__global__ __launch_bounds__(256) void greduce2(const uint* __restrict__ rmaxU,
                                                const uint* __restrict__ gminU,
                                                float* __restrict__ stat)
{
  __shared__ float red[4];
  int t = threadIdx.x;
  float mx = -3.4e38f;
  for (int i=t;i<NN;i+=256) mx = fmaxf(mx, fdec(rmaxU[i]));
  float gmx = blkMax(mx, red);
  if (t==0){
    float gmn = fdec(gminU[0]);
    stat[0] = gmn;
    stat[1] = 1.f/(gmx-gmn);
  }
}

// ---------- single-matrix: K8 = fp8(exp((M0 - rowmax)*scale)); optional M out ----------
__global__ __launch_bounds__(256) void transform_s(const unsigned short* __restrict__ stage,
                                                   uchar* __restrict__ K8m,
                                                   const uint* __restrict__ rmaxU,
                                                   const float* __restrict__ stat,
                                                   float* __restrict__ Mout)
{
  const float gmin = stat[0], scale = stat[1];
  const uint4* Km = (const uint4*)stage;
  uint2* K8 = (uint2*)K8m;
  const bool wM = (Mout != nullptr);
  const int total8 = (NN*NN)/8;
  for (int f = blockIdx.x*256 + threadIdx.x; f < total8; f += 256*256){
    int i = f >> 9;
    float rm = fdec(rmaxU[i]);
    float e[8]; unpack8(Km[f], e);
    float kx[8];
#pragma unroll
    for (int k=0;k<8;++k) kx[k] = __expf((e[k]-rm)*scale);
    uint2 o;
    o.x = e8(kx[0]) | (e8(kx[1])<<8) | (e8(kx[2])<<16) | (e8(kx[3])<<24);
    o.y = e8(kx[4]) | (e8(kx[5])<<8) | (e8(kx[6])<<16) | (e8(kx[7])<<24);
    K8[f] = o;
    if (wM){
      float4 o1, o2;
      o1.x=(e[0]-gmin)*scale; o1.y=(e[1]-gmin)*scale; o1.z=(e[2]-gmin)*scale; o1.w=(e[3]-gmin)*scale;
      o2.x=(e[4]-gmin)*scale; o2.y=(e[5]-gmin)*scale; o2.z=(e[6]-gmin)*scale; o2.w=(e[7]-gmin)*scale;
      float4* mp = (float4*)(Mout + (size_t)f*8);
      mp[0]=o1; mp[1]=o2;
    }
  }
}

// ---------- fused sinkhorn iteration over fp8 K (batched 4 matrices) ----------
__global__ __launch_bounds__(256) void sink_fused(const uchar* __restrict__ K8base,
                                                  const float* __restrict__ vv,
                                                  unsigned short* __restrict__ part)
{
  __shared__ float red[4];
  const int m = blockIdx.y, b = blockIdx.x, t = threadIdx.x;
  const int i0 = b*CHUNK;
  const uchar* K8 = K8base + (size_t)m*NN*NN;
  const float4* v4 = (const float4*)(vv + (size_t)m*NN);
  float vs[16];
  {
    float4 A=v4[t*4+0], B=v4[t*4+1], C=v4[t*4+2], D=v4[t*4+3];
    vs[0]=A.x; vs[1]=A.y; vs[2]=A.z; vs[3]=A.w;
    vs[4]=B.x; vs[5]=B.y; vs[6]=B.z; vs[7]=B.w;
    vs[8]=C.x; vs[9]=C.y; vs[10]=C.z; vs[11]=C.w;
    vs[12]=D.x; vs[13]=D.y; vs[14]=D.z; vs[15]=D.w;
  }
  float colacc[16];
#pragma unroll
  for (int k=0;k<16;++k) colacc[k]=0.f;
  for (int r=0;r<CHUNK;++r){
    uint4 kw = ((const uint4*)(K8 + (size_t)(i0+r)*NN))[t];
    float e[16];
    d8x4(kw.x, e); d8x4(kw.y, e+4); d8x4(kw.z, e+8); d8x4(kw.w, e+12);
    float dot = 0.f;
#pragma unroll
    for (int k=0;k<16;++k) dot += e[k]*vs[k];
    float rowsum = blkSum(dot, red);
    float ur = RVAL / rowsum;
#pragma unroll
    for (int k=0;k<16;++k) colacc[k] += e[k]*ur;
  }
  unsigned short* prow = part + ((size_t)m*NCH + b)*NN;
  ((uint4*)prow)[t*2]   = pack8(colacc);
  ((uint4*)prow)[t*2+1] = pack8(colacc+8);
}

// ---------- column finish: v[j] = R / sum_b part[m][b][j] ----------
__global__ __launch_bounds__(256) void colfin_b(const unsigned short* __restrict__ part,
                                                float* __restrict__ vv)
{
  __shared__ float lds[16][16][8];
  const int m = blockIdx.y, bx = blockIdx.x, t = threadIdx.x;
  const int g = t & 15;
  const int tq = t >> 4;
  const uint4* pb = (const uint4*)(part + (size_t)m*NCH*NN);
  float acc[8];
#pragma unroll
  for (int k=0;k<8;++k) acc[k]=0.f;
#pragma unroll 4
  for (int s=0;s<16;++s){
    int b = tq + s*16;
    float e[8]; unpack8(pb[(size_t)b*512 + bx*16 + g], e);
#pragma unroll
    for (int k=0;k<8;++k) acc[k] += e[k];
  }
#pragma unroll
  for (int k=0;k<8;++k) lds[tq][g][k] = acc[k];
  __syncthreads();
  if (t < 128){
    int gg = t >> 3, c = t & 7;
    float s = 0.f;
#pragma unroll
    for (int q=0;q<16;++q) s += lds[q][gg][c];
    vv[(size_t)m*NN + bx*128 + gg*8 + c] = RVAL / s;
  }
}

// ---------- final: y = Kv ; P = K v_j / y ; per-row loss partial ----------
__global__ __launch_bounds__(256) void loss2_b(const uchar* __restrict__ K8base,
                                               const float* __restrict__ vv,
                                               float* __restrict__ accf,
                                               float* __restrict__ Pout, int finalm)
{
  __shared__ float red[4];
  int m = blockIdx.y, i = blockIdx.x, t = threadIdx.x;
  const uint4* row = (const uint4*)(K8base + ((size_t)m*NN + i)*NN);
  const float4* v4 = (const float4*)(vv + (size_t)m*NN);
  uint4 kw = row[t];
  float e[16];
  d8x4(kw.x, e); d8x4(kw.y, e+4); d8x4(kw.z, e+8); d8x4(kw.w, e+12);
  float vr[16];
  {
    float4 A=v4[t*4+0], B=v4[t*4+1], C=v4[t*4+2], D=v4[t*4+3];
    vr[0]=A.x; vr[1]=A.y; vr[2]=A.z; vr[3]=A.w;
    vr[4]=B.x; vr[5]=B.y; vr[6]=B.z; vr[7]=B.w;
    vr[8]=C.x; vr[9]=C.y; vr[10]=C.z; vr[11]=C.w;
    vr[12]=D.x; vr[13]=D.y; vr[14]=D.z; vr[15]=D.w;
  }
  float s = 0.f;
#pragma unroll
  for (int k=0;k<16;++k) s += e[k]*vr[k];
  float y = blkSum(s, red);
  float invy = 1.f / y;
  const bool wp = (m==finalm) && (Pout != nullptr);
  const int j0 = t*16;
  float p[16];
#pragma unroll
  for (int k=0;k<16;++k) p[k] = e[k]*vr[k]*invy;
  if (wp){
    float4* pp = (float4*)(Pout + (size_t)i*NN + j0);
#pragma unroll
    for (int q=0;q<4;++q){
      float4 o; o.x=p[q*4]; o.y=p[q*4+1]; o.z=p[q*4+2]; o.w=p[q*4+3];
      pp[q]=o;
    }
  }
  float local = 0.f;
#pragma unroll
  for (int k=0;k<16;++k){
    float d = p[k] - ((j0+k)==i ? 1.f : 0.f);
    local += d*d;
  }
  float tot = blkSum(local, red);
  if (t==0) accf[(size_t)m*NN + i] = tot;
}

// ---------- deterministic loss reduce: out = sqrt(sum accf) ----------
__global__ __launch_bounds__(256) void lossfin2(const float* __restrict__ accf,
                                                float* __restrict__ outslot)
{
  __shared__ float red[4];
  int t = threadIdx.x;
  float s = 0.f;
#pragma unroll
  for (int q=0;q<16;++q) s += accf[t + q*256];
  float tot = blkSum(s, red);
  if (t==0) *outslot = sqrtf(tot);
}

__global__ void sumloss(float* __restrict__ out)
{
  if (threadIdx.x==0) out[0] = out[1]+out[2]+out[3]+out[4];
}

extern "C" void kernel_launch(void* const* d_in, const int* in_sizes, int n_in,
                              void* d_out, int out_size, void* d_ws, size_t ws_size,
                              hipStream_t stream)
{
  (void)in_sizes; (void)n_in; (void)out_size; (void)ws_size;
  const float* f_s  = (const float*)d_in[1];
  const float* l_s  = (const float*)d_in[2];
  const float* f_t  = (const float*)d_in[3];
  const float* l_t  = (const float*)d_in[4];
  const float* W_es = (const float*)d_in[5];
  const float* b_es = (const float*)d_in[6];
  const float* W_et = (const float*)d_in[7];
  const float* b_et = (const float*)d_in[8];
  const float* W_gs = (const float*)d_in[9];
  const float* b_gs = (const float*)d_in[10];
  const float* W_gt = (const float*)d_in[11];
  const float* b_gt = (const float*)d_in[12];
  float* out = (float*)d_out;

  char* ws = (char*)d_ws;
  size_t off = 0;
  auto alloc = [&](size_t nbytes)->void*{
    off = (off + 255) & ~(size_t)255;
    void* p = ws + off; off += nbytes; return p;
  };
  float* f_es = (float*)alloc((size_t)NN*FF*4);
  float* f_et = (float*)alloc((size_t)NN*FF*4);
  unsigned short* f_esb = (unsigned short*)alloc((size_t)NN*FF*2);
  unsigned short* f_etb = (unsigned short*)alloc((size_t)NN*FF*2);
  unsigned short* f_gsb = (unsigned short*)alloc((size_t)NN*FF*2);
  unsigned short* f_gtb = (unsigned short*)alloc((size_t)NN*FF*2);
  float* S_s  = (float*)alloc((size_t)NN*CD*4);
  float* S_t  = (float*)alloc((size_t)NN*CD*4);
  float* w_s  = (float*)alloc(NN*4);
  float* w_t  = (float*)alloc(NN*4);
  int*   idx_s= (int*)alloc(NN*8*4);
  int*   idx_t= (int*)alloc(NN*8*4);
  uint*  rmaxU= (uint*)alloc((size_t)4*NN*4);
  uint*  gminU= (uint*)alloc(64);
  float* stat = (float*)alloc(64);
  float* v    = (float*)alloc((size_t)4*NN*4);
  float* accf = (float*)alloc((size_t)4*NN*4);
  unsigned short* part = (unsigned short*)alloc((size_t)4*NCH*NN*2);  // 8 MB
  off = (off + 255) & ~(size_t)255;
  unsigned short* stage = (unsigned short*)(ws + off);   // 32 MB bf16 M0 staging
  uchar* K8 = (uchar*)(stage + (size_t)NN*NN);           // 64 MB fp8, 4 matrices
  // knn D (64 MB fp32) overlaps stage + first half of K8 (strictly pre-OT)
  float* Dbuf = (float*)stage;
  // embed scratch also aliases stage (strictly pre-knn)
  float* epart = (float*)stage;                               // KS*NN*FF*4 = 16 MB
  unsigned short* Wt0 = (unsigned short*)((char*)stage + (size_t)KS*NN*FF*4);
  unsigned short* Wt1 = Wt0 + (size_t)FF*EK;                  // 2 MB each

  float* Pout_final = out + 5;
  float* Mout_final = out + 5 + (size_t)NN*NN;

  // ---- embeddings (MFMA split-K) ----
  transposeW<<<EK/64,256,0,stream>>>(W_es, Wt0);
  transposeW<<<EK/64,256,0,stream>>>(W_et, Wt1);
  embed_mfma<<<dim3(64,KS),256,0,stream>>>(f_s, Wt0, epart);
  reduce_l2<<<NN,128,0,stream>>>(epart, b_es, f_es, f_esb);
  embed_mfma<<<dim3(64,KS),256,0,stream>>>(f_t, Wt1, epart);
  reduce_l2<<<NN,128,0,stream>>>(epart, b_et, f_et, f_etb);

  // ---- knn path (R5-proven: materialized D + select) ----
  softmax_rows<<<NN,128,0,stream>>>(l_s, S_s, w_s);
  softmax_rows<<<NN,128,0,stream>>>(l_t, S_t, w_t);
  cos_gemm<<<dim3(64,64),256,0,stream>>>(S_s, w_s, Dbuf);
  knn_select<<<NN,256,0,stream>>>(Dbuf, idx_s);
  cos_gemm<<<dim3(64,64),256,0,stream>>>(S_t, w_t, Dbuf);
  knn_select<<<NN,256,0,stream>>>(Dbuf, idx_t);
  encoder_kernel<<<NN,128,0,stream>>>(f_es, idx_s, W_gs, b_gs, f_gsb);
  encoder_kernel<<<NN,128,0,stream>>>(f_et, idx_t, W_gt, b_gt, f_gtb);

  // ---- OT: per-matrix build (shared stage), then 4-batched sinkhorn ----
  const unsigned short* ftab[4] = { f_etb, f_gtb, f_etb, f_gtb };
  const unsigned short* fsab[4] = { f_esb, f_esb, f_gtb, f_gsb };
  const int slotab[4]  = { 1, 3, 4, 2 };   // m=3 is loss_g -> writes P/M

  stats_init<<<(4*NN+255)/256,256,0,stream>>>(v, rmaxU, gminU);
  for (int m=0; m<4; ++m){
    gemm_btb_mfma<<<dim3(64,64),256,0,stream>>>(ftab[m], fsab[m], stage,
        rmaxU + (size_t)m*NN, gminU + m);
    greduce2<<<1,256,0,stream>>>(rmaxU + (size_t)m*NN, gminU + m, stat + 2*m);
    transform_s<<<256,256,0,stream>>>(stage, K8 + (size_t)m*NN*NN,
        rmaxU + (size_t)m*NN, stat + 2*m,
        (m==3) ? Mout_final : (float*)nullptr);
  }
  for (int it=0; it<OT_ITERS; ++it){
    sink_fused<<<dim3(NCH,4),256,0,stream>>>(K8, v, part);
    colfin_b<<<dim3(32,4),256,0,stream>>>(part, v);
  }
  loss2_b<<<dim3(NN,4),256,0,stream>>>(K8, v, accf, Pout_final, 3);
  for (int m=0;m<4;++m)
    lossfin2<<<1,256,0,stream>>>(accf + (size_t)m*NN, out + slotab[m]);

  sumloss<<<1,1,0,stream>>>(out);
}

// Round 8
// 1157.208 us; speedup vs baseline: 1.7810x; 1.6010x over previous
//
#include <hip/hip_runtime.h>
#include <math.h>

#define NN 4096
#define FF 128
#define CD 100
#define OT_ITERS 20
#define RVAL (1.0f/4096.0f)
#define EK 8192
#define KS 8
#define CHUNK 16
#define NCH 256

typedef unsigned int uint;
typedef unsigned char uchar;
typedef __attribute__((ext_vector_type(8))) short bf16x8;
typedef __attribute__((ext_vector_type(4))) float f32x4;

// ---------- bf16 helpers ----------
__device__ __forceinline__ float bflo(uint u){ return __uint_as_float(u << 16); }
__device__ __forceinline__ float bfhi(uint u){ return __uint_as_float(u & 0xFFFF0000u); }
__device__ __forceinline__ unsigned short f2bf(float x){
  uint u = __float_as_uint(x);
  u += 0x7FFFu + ((u >> 16) & 1u);
  return (unsigned short)(u >> 16);
}
__device__ __forceinline__ void unpack8(uint4 kk, float* e){
  e[0]=bflo(kk.x); e[1]=bfhi(kk.x); e[2]=bflo(kk.y); e[3]=bfhi(kk.y);
  e[4]=bflo(kk.z); e[5]=bfhi(kk.z); e[6]=bflo(kk.w); e[7]=bfhi(kk.w);
}
__device__ __forceinline__ uint4 pack8(const float* e){
  union { unsigned short us[8]; uint4 u4; } pk;
#pragma unroll
  for (int k=0;k<8;++k) pk.us[k]=f2bf(e[k]);
  return pk.u4;
}

// ---------- fp8 e4m3-style codec (domain K in [1/e, 1], always normal) ----------
__device__ __forceinline__ uint e8(float f){
  uint u = __float_as_uint(f);
  uint m23 = u & 0x7FFFFFu;
  uint rnd = 0x7FFFFu + ((m23 >> 20) & 1u);
  uint mr  = m23 + rnd;
  uint e   = (u >> 23) & 0xFFu;
  uint m3  = (mr >> 20) & 7u;
  e += (mr >> 23);
  return (((e - 120u) << 3) | m3) & 0x7Fu;
}
__device__ __forceinline__ void d8x4(uint w, float* e){
  e[0]=__uint_as_float((( w      & 0x7Fu)<<20)+0x3C000000u);
  e[1]=__uint_as_float((((w>> 8) & 0x7Fu)<<20)+0x3C000000u);
  e[2]=__uint_as_float((((w>>16) & 0x7Fu)<<20)+0x3C000000u);
  e[3]=__uint_as_float((((w>>24) & 0x7Fu)<<20)+0x3C000000u);
}

// ---------- wave/block reduce helpers (wave = 64) ----------
__device__ __forceinline__ float waveSum(float v){
#pragma unroll
  for (int o=32;o>0;o>>=1) v += __shfl_down(v,o);
  return v;
}
__device__ __forceinline__ float waveMax(float v){
#pragma unroll
  for (int o=32;o>0;o>>=1) v = fmaxf(v,__shfl_down(v,o));
  return v;
}
__device__ __forceinline__ float waveMin(float v){
#pragma unroll
  for (int o=32;o>0;o>>=1) v = fminf(v,__shfl_down(v,o));
  return v;
}
__device__ __forceinline__ float blkSum(float v, float* red){
  v = waveSum(v);
  if ((threadIdx.x&63)==0) red[threadIdx.x>>6] = v;
  __syncthreads();
  float r = red[0]+red[1]+red[2]+red[3];
  __syncthreads();
  return r;
}

// ---------- W transpose+convert: Wt[n][k] bf16 from W[k][n] fp32 ----------
__global__ __launch_bounds__(256) void transposeW(const float* __restrict__ W,
                                                  unsigned short* __restrict__ Wt)
{
  __shared__ unsigned short T[128][72];
  const int k0 = blockIdx.x*64, tid = threadIdx.x;
#pragma unroll
  for (int it=0; it<8; ++it){
    int f = tid + it*256;
    int r = f >> 5, c4 = f & 31;
    float4 v = *(const float4*)&W[(size_t)(k0+r)*FF + c4*4];
    T[c4*4+0][r]=f2bf(v.x); T[c4*4+1][r]=f2bf(v.y);
    T[c4*4+2][r]=f2bf(v.z); T[c4*4+3][r]=f2bf(v.w);
  }
  __syncthreads();
#pragma unroll
  for (int it=0; it<4; ++it){
    int f = tid + it*256;
    int n = f >> 3, c8 = f & 7;
    *(uint4*)&Wt[(size_t)n*EK + k0 + c8*8] = *(uint4*)&T[n][c8*8];
  }
}

// ---------- MFMA embed GEMM (split-K=8): part[ks][4096][128] ----------
__global__ __launch_bounds__(256) void embed_mfma(const float* __restrict__ A,
                                                  const unsigned short* __restrict__ Wt,
                                                  float* __restrict__ part)
{
  __shared__ unsigned short Al[64][72];
  __shared__ unsigned short Wl[128][72];
  const int tid = threadIdx.x;
  const int m0 = blockIdx.x * 64;
  const int kc = blockIdx.y * (EK/KS);
  const int w = tid >> 6, l = tid & 63;
  const int wr = w >> 1, wc = w & 1;
  const int lrow = l & 15, lk = (l >> 4) * 8;
  f32x4 acc[2][4];
#pragma unroll
  for (int mi=0;mi<2;++mi)
#pragma unroll
    for (int ni=0;ni<4;++ni) acc[mi][ni] = (f32x4){0.f,0.f,0.f,0.f};

  for (int k0 = kc; k0 < kc + EK/KS; k0 += 64) {
#pragma unroll
    for (int it = 0; it < 4; ++it) {
      int f = tid + it*256;
      int r = f >> 4, c4 = f & 15;
      float4 a4 = *(const float4*)&A[(size_t)(m0+r)*EK + k0 + c4*4];
      union { unsigned short us[4]; uint2 u2; } pk;
      pk.us[0]=f2bf(a4.x); pk.us[1]=f2bf(a4.y); pk.us[2]=f2bf(a4.z); pk.us[3]=f2bf(a4.w);
      *(uint2*)&Al[r][c4*4] = pk.u2;
    }
#pragma unroll
    for (int it = 0; it < 4; ++it) {
      int f = tid + it*256;
      int r = f >> 3, c8 = f & 7;
      *(uint4*)&Wl[r][c8*8] = *(const uint4*)&Wt[(size_t)r*EK + k0 + c8*8];
    }
    __syncthreads();
#pragma unroll
    for (int ksub = 0; ksub < 2; ++ksub) {
      bf16x8 af[2], bfr[4];
#pragma unroll
      for (int mi=0;mi<2;++mi) af[mi] = *(bf16x8*)&Al[wr*32+mi*16+lrow][ksub*32+lk];
#pragma unroll
      for (int ni=0;ni<4;++ni) bfr[ni] = *(bf16x8*)&Wl[wc*64+ni*16+lrow][ksub*32+lk];
#pragma unroll
      for (int mi=0;mi<2;++mi)
#pragma unroll
        for (int ni=0;ni<4;++ni)
          acc[mi][ni] = __builtin_amdgcn_mfma_f32_16x16x32_bf16(af[mi], bfr[ni], acc[mi][ni], 0,0,0);
    }
    __syncthreads();
  }
#pragma unroll
  for (int mi=0;mi<2;++mi)
#pragma unroll
    for (int ni=0;ni<4;++ni)
#pragma unroll
      for (int r=0;r<4;++r) {
        int row = m0 + wr*32 + mi*16 + (l>>4)*4 + r;
        int col = wc*64 + ni*16 + lrow;
        part[((size_t)blockIdx.y*NN + row)*FF + col] = acc[mi][ni][r];
      }
}

// ---------- reduce split-K partials + bias + l2norm -> fp32 and bf16 ----------
__global__ __launch_bounds__(128) void reduce_l2(const float* __restrict__ part,
                                                 const float* __restrict__ bias,
                                                 float* __restrict__ out,
                                                 unsigned short* __restrict__ outb)
{
  __shared__ float red[2];
  int i = blockIdx.x, t = threadIdx.x;
  float s = bias[t];
#pragma unroll
  for (int ks=0; ks<KS; ++ks) s += part[((size_t)ks*NN + i)*FF + t];
  float q = waveSum(s*s);
  if ((t&63)==0) red[t>>6]=q;
  __syncthreads();
  float val = s / sqrtf(red[0]+red[1]);
  out[(size_t)i*FF+t] = val;
  outb[(size_t)i*FF+t] = f2bf(val);
}

// ---------- softmax rows of l[4096x100] -> S, w = ||S_row|| ----------
__global__ __launch_bounds__(128) void softmax_rows(const float* __restrict__ l,
                                                    float* __restrict__ S,
                                                    float* __restrict__ w)
{
  __shared__ float sm[2], ss[2], sq[2];
  int i = blockIdx.x, t = threadIdx.x;
  int lane = t & 63, wid = t >> 6;
  float x = (t < CD) ? l[(size_t)i*CD + t] : -3.4e38f;
  float m = waveMax(x);
  if (lane==0) sm[wid]=m;
  __syncthreads();
  m = fmaxf(sm[0], sm[1]);
  float e = (t < CD) ? __expf(x - m) : 0.f;
  float s = waveSum(e);
  if (lane==0) ss[wid]=s;
  __syncthreads();
  float tot = ss[0]+ss[1];
  float sv = e / tot;
  if (t < CD) S[(size_t)i*CD + t] = sv;
  float q = waveSum(sv*sv);
  if (lane==0) sq[wid]=q;
  __syncthreads();
  if (t==0) w[i] = sqrtf(sq[0]+sq[1]);
}

// ---------- cos matrix: D[i][j] = (S_i . S_j)/max(w_i w_j, eps), diag = -2 ----------
__global__ __launch_bounds__(256) void cos_gemm(const float* __restrict__ S,
                                                const float* __restrict__ w,
                                                float* __restrict__ D)
{
  __shared__ float As[64][108];
  __shared__ float Bs[100][68];
  const int tid = threadIdx.x;
  const int tc = tid & 15, tr = tid >> 4;
  const int i0 = blockIdx.y*64, j0 = blockIdx.x*64;
  for (int f = tid; f < 64*25; f += 256){
    int r = f/25, c4 = f%25;
    *(float4*)&As[r][c4*4] = *(const float4*)&S[(size_t)(i0+r)*CD + c4*4];
  }
  for (int f = tid; f < 64*25; f += 256){
    int r = f/25, c4 = f%25;
    float4 bv = *(const float4*)&S[(size_t)(j0+r)*CD + c4*4];
    Bs[c4*4+0][r]=bv.x; Bs[c4*4+1][r]=bv.y; Bs[c4*4+2][r]=bv.z; Bs[c4*4+3][r]=bv.w;
  }
  __syncthreads();
  float acc[4][4];
#pragma unroll
  for (int a=0;a<4;++a)
#pragma unroll
    for (int b=0;b<4;++b) acc[a][b]=0.f;
  for (int kk=0; kk<100; kk+=4){
    float a[4][4];
#pragma unroll
    for (int q=0;q<4;++q) *(float4*)a[q] = *(const float4*)&As[tr*4+q][kk];
#pragma unroll
    for (int t4=0;t4<4;++t4){
      float4 b = *(const float4*)&Bs[kk+t4][tc*4];
#pragma unroll
      for (int rr=0;rr<4;++rr){
        float av = a[rr][t4];
        acc[rr][0] += av*b.x; acc[rr][1] += av*b.y;
        acc[rr][2] += av*b.z; acc[rr][3] += av*b.w;
      }
    }
  }
  float wi[4], wj[4];
#pragma unroll
  for (int q=0;q<4;++q){ wi[q] = w[i0+tr*4+q]; wj[q] = w[j0+tc*4+q]; }
#pragma unroll
  for (int rr=0;rr<4;++rr){
    int i = i0+tr*4+rr;
    float4 o;
    float* op = (float*)&o;
#pragma unroll
    for (int cc=0;cc<4;++cc){
      int j = j0+tc*4+cc;
      float val = acc[rr][cc] / fmaxf(wi[rr]*wj[cc], 1e-7f);
      op[cc] = (i==j) ? -2.f : val;
    }
    *(float4*)&D[(size_t)i*NN + j0 + tc*4] = o;
  }
}

// ---------- top-7 select per row of D; idx[i][0] = i ----------
__global__ __launch_bounds__(256) void knn_select(const float* __restrict__ D,
                                                  int* __restrict__ idx)
{
  __shared__ float redv[256];
  __shared__ int   redi[256];
  int i = blockIdx.x, tid = threadIdx.x;
  float bv[7]; int bi[7];
#pragma unroll
  for (int m=0;m<7;++m){ bv[m]=-3.4e38f; bi[m]=-1; }
  const float4* row4 = (const float4*)&D[(size_t)i*NN];
#pragma unroll
  for (int s=0;s<4;++s){
    int j4 = tid + s*256;
    float4 vv = row4[j4];
    float cv[4] = {vv.x, vv.y, vv.z, vv.w};
#pragma unroll
    for (int q=0;q<4;++q){
      if (cv[q] > bv[6]) {
        int m = 6;
        while (m > 0 && cv[q] > bv[m-1]) { bv[m]=bv[m-1]; bi[m]=bi[m-1]; --m; }
        bv[m]=cv[q]; bi[m]=j4*4+q;
      }
    }
  }
  if (tid==0) idx[(size_t)i*8] = i;
  for (int m=0;m<7;++m) {
    redv[tid]=bv[0]; redi[tid]=tid;
    __syncthreads();
    for (int s=128;s>=1;s>>=1) {
      if (tid < s) {
        if (redv[tid+s] > redv[tid]) { redv[tid]=redv[tid+s]; redi[tid]=redi[tid+s]; }
      }
      __syncthreads();
    }
    int wt = redi[0];
    if (tid == wt) {
      idx[(size_t)i*8 + 1 + m] = bi[0];
#pragma unroll
      for (int q=0;q<6;++q){ bv[q]=bv[q+1]; bi[q]=bi[q+1]; }
      bv[6]=-3.4e38f; bi[6]=-1;
    }
    __syncthreads();
  }
}

// ---------- encoder: outb = bf16(l2norm(concat(h, mean(h[idx])) @ W + b)) ----------
__global__ __launch_bounds__(128) void encoder_kernel(const float* __restrict__ h,
                                                      const int* __restrict__ idx,
                                                      const float* __restrict__ W,
                                                      const float* __restrict__ bias,
                                                      unsigned short* __restrict__ outb)
{
  __shared__ float hin[256];
  __shared__ float sred[2];
  int i = blockIdx.x, t = threadIdx.x;
  float hv = h[(size_t)i*FF + t];
  float agg = 0.f;
#pragma unroll
  for (int m=0;m<8;++m) agg += h[(size_t)idx[i*8+m]*FF + t];
  agg *= 0.125f;
  hin[t] = hv; hin[FF + t] = agg;
  __syncthreads();
  float acc = bias[t];
  for (int k=0;k<256;++k) acc += hin[k] * W[(size_t)k*FF + t];
  float s = waveSum(acc*acc);
  int lane = t & 63, wid = t >> 6;
  if (lane==0) sred[wid]=s;
  __syncthreads();
  float tot = sred[0]+sred[1];
  outb[(size_t)i*FF + t] = f2bf(acc / sqrtf(tot));
}

// ---------- MFMA: stage bf16 = A bf16 [4096x128] @ B^T (no stats) ----------
__global__ __launch_bounds__(256) void gemm_btb_mfma(const unsigned short* __restrict__ A,
                                                     const unsigned short* __restrict__ B,
                                                     unsigned short* __restrict__ C)
{
  __shared__ unsigned short Al[64][136];
  __shared__ unsigned short Bl[64][136];
  const int tid = threadIdx.x;
  const int i0 = blockIdx.y*64, j0 = blockIdx.x*64;
#pragma unroll
  for (int it=0; it<4; ++it){
    int f = tid + it*256;
    int r = f >> 4, c8 = f & 15;
    *(uint4*)&Al[r][c8*8] = *(const uint4*)&A[(size_t)(i0+r)*FF + c8*8];
    *(uint4*)&Bl[r][c8*8] = *(const uint4*)&B[(size_t)(j0+r)*FF + c8*8];
  }
  __syncthreads();
  const int w = tid>>6, l = tid&63;
  const int wr = w>>1, wc = w&1;
  const int lrow = l&15, lk = (l>>4)*8;
  f32x4 acc[2][2];
#pragma unroll
  for (int mi=0;mi<2;++mi)
#pragma unroll
    for (int ni=0;ni<2;++ni) acc[mi][ni] = (f32x4){0.f,0.f,0.f,0.f};
#pragma unroll
  for (int ks=0; ks<4; ++ks){
    bf16x8 af[2], bfm[2];
#pragma unroll
    for (int mi=0;mi<2;++mi) af[mi] = *(bf16x8*)&Al[wr*32+mi*16+lrow][ks*32+lk];
#pragma unroll
    for (int ni=0;ni<2;++ni) bfm[ni] = *(bf16x8*)&Bl[wc*32+ni*16+lrow][ks*32+lk];
#pragma unroll
    for (int mi=0;mi<2;++mi)
#pragma unroll
      for (int ni=0;ni<2;++ni)
        acc[mi][ni] = __builtin_amdgcn_mfma_f32_16x16x32_bf16(af[mi], bfm[ni], acc[mi][ni], 0,0,0);
  }
  __syncthreads();
  unsigned short (*Cl)[72] = (unsigned short(*)[72])&Al[0][0];
#pragma unroll
  for (int mi=0;mi<2;++mi)
#pragma unroll
    for (int ni=0;ni<2;++ni)
#pragma unroll
      for (int r=0;r<4;++r){
        int row = wr*32 + mi*16 + (l>>4)*4 + r;
        int col = wc*32 + ni*16 + lrow;
        Cl[row][col] = f2bf(acc[mi][ni][r]);
      }
  __syncthreads();
#pragma unroll
  for (int it=0; it<2; ++it){
    int f = tid + it*256;
    int r = f >> 3, c8 = f & 7;
    *(uint4*)&C[(size_t)(i0+r)*NN + j0 + c8*8] = *(uint4*)&Cl[r][c8*8];
  }
}

// ---------- single-matrix per-row max/min over bf16 stage ----------
__global__ __launch_bounds__(256) void rowstat_s(const unsigned short* __restrict__ stage,
                                                 float* __restrict__ rmax,
                                                 float* __restrict__ rmin)
{
  __shared__ float r1[4], r2[4];
  int i = blockIdx.x, t = threadIdx.x;
  const uint4* row = (const uint4*)(stage + (size_t)i*NN);
  float mx=-3.4e38f, mn=3.4e38f;
#pragma unroll
  for (int s=0;s<2;++s){
    float e[8]; unpack8(row[t + s*256], e);
#pragma unroll
    for (int k=0;k<8;++k){ mx = fmaxf(mx,e[k]); mn = fminf(mn,e[k]); }
  }
  mx = waveMax(mx); mn = waveMin(mn);
  int lane = t & 63, wid = t >> 6;
  if (lane==0){ r1[wid]=mx; r2[wid]=mn; }
  __syncthreads();
  if (t==0){
    rmax[i] = fmaxf(fmaxf(r1[0],r1[1]),fmaxf(r1[2],r1[3]));
    rmin[i] = fminf(fminf(r2[0],r2[1]),fminf(r2[2],r2[3]));
  }
}

// ---------- single-matrix stat finalize: stat = {gmin, 1/(gmax-gmin)} ----------
__global__ __launch_bounds__(256) void greduce_s(const float* __restrict__ rmax,
                                                 const float* __restrict__ rmin,
                                                 float* __restrict__ stat)
{
  __shared__ float r1[4], r2[4];
  int t = threadIdx.x;
  float mx=-3.4e38f, mn=3.4e38f;
  for (int i=t; i<NN; i+=256){
    mx = fmaxf(mx, rmax[i]);
    mn = fminf(mn, rmin[i]);
  }
  mx = waveMax(mx); mn = waveMin(mn);
  int lane = t & 63, wid = t >> 6;
  if (lane==0){ r1[wid]=mx; r2[wid]=mn; }
  __syncthreads();
  if (t==0){
    float gmx = fmaxf(fmaxf(r1[0],r1[1]),fmaxf(r1[2],r1[3]));
    float gmn = fminf(fminf(r2[0],r2[1]),fminf(r2[2],r2[3]));
    stat[0] = gmn;
    stat[1] = 1.f/(gmx-gmn);
  }
}

// ---------- single-matrix: K8 = fp8(exp((M0 - rowmax)*scale)); optional M out ----------
__global__ __launch_bounds__(256) void transform_s(const unsigned short* __restrict__ stage,
                                                   uchar* __restrict__ K8m,
                                                   const float* __restrict__ rmax,
                                                   const float* __restrict__ stat,
                                                   float* __restrict__ Mout)
{
  const float gmin = stat[0], scale = stat[1];
  const uint4* Km = (const uint4*)stage;
  uint2* K8 = (uint2*)K8m;
  const bool wM = (Mout != nullptr);
  const int total8 = (NN*NN)/8;
  for (int f = blockIdx.x*256 + threadIdx.x; f < total8; f += 256*256){
    int i = f >> 9;
    float rm = rmax[i];
    float e[8]; unpack8(Km[f], e);
    float kx[8];
#pragma unroll
    for (int k=0;k<8;++k) kx[k] = __expf((e[k]-rm)*scale);
    uint2 o;
    o.x = e8(kx[0]) | (e8(kx[1])<<8) | (e8(kx[2])<<16) | (e8(kx[3])<<24);
    o.y = e8(kx[4]) | (e8(kx[5])<<8) | (e8(kx[6])<<16) | (e8(kx[7])<<24);
    K8[f] = o;
    if (wM){
      float4 o1, o2;
      o1.x=(e[0]-gmin)*scale; o1.y=(e[1]-gmin)*scale; o1.z=(e[2]-gmin)*scale; o1.w=(e[3]-gmin)*scale;
      o2.x=(e[4]-gmin)*scale; o2.y=(e[5]-gmin)*scale; o2.z=(e[6]-gmin)*scale; o2.w=(e[7]-gmin)*scale;
      float4* mp = (float4*)(Mout + (size_t)f*8);
      mp[0]=o1; mp[1]=o2;
    }
  }
}

// ---------- init: v=1 for all 4 matrices ----------
__global__ void vinit4(float* __restrict__ v)
{
  int g = blockIdx.x*256 + threadIdx.x;
  if (g < 4*NN) v[g] = 1.f;
}

// ---------- fused sinkhorn iteration over fp8 K (batched 4 matrices) ----------
__global__ __launch_bounds__(256) void sink_fused(const uchar* __restrict__ K8base,
                                                  const float* __restrict__ vv,
                                                  unsigned short* __restrict__ part)
{
  __shared__ float red[4];
  const int m = blockIdx.y, b = blockIdx.x, t = threadIdx.x;
  const int i0 = b*CHUNK;
  const uchar* K8 = K8base + (size_t)m*NN*NN;
  const float4* v4 = (const float4*)(vv + (size_t)m*NN);
  float vs[16];
  {
    float4 A=v4[t*4+0], B=v4[t*4+1], C=v4[t*4+2], D=v4[t*4+3];
    vs[0]=A.x; vs[1]=A.y; vs[2]=A.z; vs[3]=A.w;
    vs[4]=B.x; vs[5]=B.y; vs[6]=B.z; vs[7]=B.w;
    vs[8]=C.x; vs[9]=C.y; vs[10]=C.z; vs[11]=C.w;
    vs[12]=D.x; vs[13]=D.y; vs[14]=D.z; vs[15]=D.w;
  }
  float colacc[16];
#pragma unroll
  for (int k=0;k<16;++k) colacc[k]=0.f;
  for (int r=0;r<CHUNK;++r){
    uint4 kw = ((const uint4*)(K8 + (size_t)(i0+r)*NN))[t];
    float e[16];
    d8x4(kw.x, e); d8x4(kw.y, e+4); d8x4(kw.z, e+8); d8x4(kw.w, e+12);
    float dot = 0.f;
#pragma unroll
    for (int k=0;k<16;++k) dot += e[k]*vs[k];
    float rowsum = blkSum(dot, red);
    float ur = RVAL / rowsum;
#pragma unroll
    for (int k=0;k<16;++k) colacc[k] += e[k]*ur;
  }
  unsigned short* prow = part + ((size_t)m*NCH + b)*NN;
  ((uint4*)prow)[t*2]   = pack8(colacc);
  ((uint4*)prow)[t*2+1] = pack8(colacc+8);
}

// ---------- column finish: v[j] = R / sum_b part[m][b][j] ----------
__global__ __launch_bounds__(256) void colfin_b(const unsigned short* __restrict__ part,
                                                float* __restrict__ vv)
{
  __shared__ float lds[16][16][8];
  const int m = blockIdx.y, bx = blockIdx.x, t = threadIdx.x;
  const int g = t & 15;
  const int tq = t >> 4;
  const uint4* pb = (const uint4*)(part + (size_t)m*NCH*NN);
  float acc[8];
#pragma unroll
  for (int k=0;k<8;++k) acc[k]=0.f;
#pragma unroll 4
  for (int s=0;s<16;++s){
    int b = tq + s*16;
    float e[8]; unpack8(pb[(size_t)b*512 + bx*16 + g], e);
#pragma unroll
    for (int k=0;k<8;++k) acc[k] += e[k];
  }
#pragma unroll
  for (int k=0;k<8;++k) lds[tq][g][k] = acc[k];
  __syncthreads();
  if (t < 128){
    int gg = t >> 3, c = t & 7;
    float s = 0.f;
#pragma unroll
    for (int q=0;q<16;++q) s += lds[q][gg][c];
    vv[(size_t)m*NN + bx*128 + gg*8 + c] = RVAL / s;
  }
}

// ---------- final: y = Kv ; P = K v_j / y ; per-row loss partial ----------
__global__ __launch_bounds__(256) void loss2_b(const uchar* __restrict__ K8base,
                                               const float* __restrict__ vv,
                                               float* __restrict__ accf,
                                               float* __restrict__ Pout, int finalm)
{
  __shared__ float red[4];
  int m = blockIdx.y, i = blockIdx.x, t = threadIdx.x;
  const uint4* row = (const uint4*)(K8base + ((size_t)m*NN + i)*NN);
  const float4* v4 = (const float4*)(vv + (size_t)m*NN);
  uint4 kw = row[t];
  float e[16];
  d8x4(kw.x, e); d8x4(kw.y, e+4); d8x4(kw.z, e+8); d8x4(kw.w, e+12);
  float vr[16];
  {
    float4 A=v4[t*4+0], B=v4[t*4+1], C=v4[t*4+2], D=v4[t*4+3];
    vr[0]=A.x; vr[1]=A.y; vr[2]=A.z; vr[3]=A.w;
    vr[4]=B.x; vr[5]=B.y; vr[6]=B.z; vr[7]=B.w;
    vr[8]=C.x; vr[9]=C.y; vr[10]=C.z; vr[11]=C.w;
    vr[12]=D.x; vr[13]=D.y; vr[14]=D.z; vr[15]=D.w;
  }
  float s = 0.f;
#pragma unroll
  for (int k=0;k<16;++k) s += e[k]*vr[k];
  float y = blkSum(s, red);
  float invy = 1.f / y;
  const bool wp = (m==finalm) && (Pout != nullptr);
  const int j0 = t*16;
  float p[16];
#pragma unroll
  for (int k=0;k<16;++k) p[k] = e[k]*vr[k]*invy;
  if (wp){
    float4* pp = (float4*)(Pout + (size_t)i*NN + j0);
#pragma unroll
    for (int q=0;q<4;++q){
      float4 o; o.x=p[q*4]; o.y=p[q*4+1]; o.z=p[q*4+2]; o.w=p[q*4+3];
      pp[q]=o;
    }
  }
  float local = 0.f;
#pragma unroll
  for (int k=0;k<16;++k){
    float d = p[k] - ((j0+k)==i ? 1.f : 0.f);
    local += d*d;
  }
  float tot = blkSum(local, red);
  if (t==0) accf[(size_t)m*NN + i] = tot;
}

// ---------- deterministic loss reduce: out = sqrt(sum accf) ----------
__global__ __launch_bounds__(256) void lossfin2(const float* __restrict__ accf,
                                                float* __restrict__ outslot)
{
  __shared__ float red[4];
  int t = threadIdx.x;
  float s = 0.f;
#pragma unroll
  for (int q=0;q<16;++q) s += accf[t + q*256];
  float tot = blkSum(s, red);
  if (t==0) *outslot = sqrtf(tot);
}

__global__ void sumloss(float* __restrict__ out)
{
  if (threadIdx.x==0) out[0] = out[1]+out[2]+out[3]+out[4];
}

extern "C" void kernel_launch(void* const* d_in, const int* in_sizes, int n_in,
                              void* d_out, int out_size, void* d_ws, size_t ws_size,
                              hipStream_t stream)
{
  (void)in_sizes; (void)n_in; (void)out_size; (void)ws_size;
  const float* f_s  = (const float*)d_in[1];
  const float* l_s  = (const float*)d_in[2];
  const float* f_t  = (const float*)d_in[3];
  const float* l_t  = (const float*)d_in[4];
  const float* W_es = (const float*)d_in[5];
  const float* b_es = (const float*)d_in[6];
  const float* W_et = (const float*)d_in[7];
  const float* b_et = (const float*)d_in[8];
  const float* W_gs = (const float*)d_in[9];
  const float* b_gs = (const float*)d_in[10];
  const float* W_gt = (const float*)d_in[11];
  const float* b_gt = (const float*)d_in[12];
  float* out = (float*)d_out;

  char* ws = (char*)d_ws;
  size_t off = 0;
  auto alloc = [&](size_t nbytes)->void*{
    off = (off + 255) & ~(size_t)255;
    void* p = ws + off; off += nbytes; return p;
  };
  float* f_es = (float*)alloc((size_t)NN*FF*4);
  float* f_et = (float*)alloc((size_t)NN*FF*4);
  unsigned short* f_esb = (unsigned short*)alloc((size_t)NN*FF*2);
  unsigned short* f_etb = (unsigned short*)alloc((size_t)NN*FF*2);
  unsigned short* f_gsb = (unsigned short*)alloc((size_t)NN*FF*2);
  unsigned short* f_gtb = (unsigned short*)alloc((size_t)NN*FF*2);
  float* S_s  = (float*)alloc((size_t)NN*CD*4);
  float* S_t  = (float*)alloc((size_t)NN*CD*4);
  float* w_s  = (float*)alloc(NN*4);
  float* w_t  = (float*)alloc(NN*4);
  int*   idx_s= (int*)alloc(NN*8*4);
  int*   idx_t= (int*)alloc(NN*8*4);
  float* rmax = (float*)alloc(NN*4);
  float* rmin = (float*)alloc(NN*4);
  float* stat = (float*)alloc(64);
  float* v    = (float*)alloc((size_t)4*NN*4);
  float* accf = (float*)alloc((size_t)4*NN*4);
  unsigned short* part = (unsigned short*)alloc((size_t)4*NCH*NN*2);  // 8 MB
  off = (off + 255) & ~(size_t)255;
  unsigned short* stage = (unsigned short*)(ws + off);   // 32 MB bf16 M0 staging
  uchar* K8 = (uchar*)(stage + (size_t)NN*NN);           // 64 MB fp8, 4 matrices
  // knn D (64 MB fp32) overlaps stage + first half of K8 (strictly pre-OT)
  float* Dbuf = (float*)stage;
  // embed scratch also aliases stage (strictly pre-knn)
  float* epart = (float*)stage;                               // KS*NN*FF*4 = 16 MB
  unsigned short* Wt0 = (unsigned short*)((char*)stage + (size_t)KS*NN*FF*4);
  unsigned short* Wt1 = Wt0 + (size_t)FF*EK;                  // 2 MB each

  float* Pout_final = out + 5;
  float* Mout_final = out + 5 + (size_t)NN*NN;

  // ---- embeddings (MFMA split-K) ----
  transposeW<<<EK/64,256,0,stream>>>(W_es, Wt0);
  transposeW<<<EK/64,256,0,stream>>>(W_et, Wt1);
  embed_mfma<<<dim3(64,KS),256,0,stream>>>(f_s, Wt0, epart);
  reduce_l2<<<NN,128,0,stream>>>(epart, b_es, f_es, f_esb);
  embed_mfma<<<dim3(64,KS),256,0,stream>>>(f_t, Wt1, epart);
  reduce_l2<<<NN,128,0,stream>>>(epart, b_et, f_et, f_etb);

  // ---- knn path ----
  softmax_rows<<<NN,128,0,stream>>>(l_s, S_s, w_s);
  softmax_rows<<<NN,128,0,stream>>>(l_t, S_t, w_t);
  cos_gemm<<<dim3(64,64),256,0,stream>>>(S_s, w_s, Dbuf);
  knn_select<<<NN,256,0,stream>>>(Dbuf, idx_s);
  cos_gemm<<<dim3(64,64),256,0,stream>>>(S_t, w_t, Dbuf);
  knn_select<<<NN,256,0,stream>>>(Dbuf, idx_t);
  encoder_kernel<<<NN,128,0,stream>>>(f_es, idx_s, W_gs, b_gs, f_gsb);
  encoder_kernel<<<NN,128,0,stream>>>(f_et, idx_t, W_gt, b_gt, f_gtb);

  // ---- OT: per-matrix build (shared stage), then 4-batched sinkhorn ----
  const unsigned short* ftab[4] = { f_etb, f_gtb, f_etb, f_gtb };
  const unsigned short* fsab[4] = { f_esb, f_esb, f_gtb, f_gsb };
  const int slotab[4]  = { 1, 3, 4, 2 };   // m=3 is loss_g -> writes P/M

  vinit4<<<(4*NN+255)/256,256,0,stream>>>(v);
  for (int m=0; m<4; ++m){
    gemm_btb_mfma<<<dim3(64,64),256,0,stream>>>(ftab[m], fsab[m], stage);
    rowstat_s<<<NN,256,0,stream>>>(stage, rmax, rmin);
    greduce_s<<<1,256,0,stream>>>(rmax, rmin, stat);
    transform_s<<<256,256,0,stream>>>(stage, K8 + (size_t)m*NN*NN,
        rmax, stat, (m==3) ? Mout_final : (float*)nullptr);
  }
  for (int it=0; it<OT_ITERS; ++it){
    sink_fused<<<dim3(NCH,4),256,0,stream>>>(K8, v, part);
    colfin_b<<<dim3(32,4),256,0,stream>>>(part, v);
  }
  loss2_b<<<dim3(NN,4),256,0,stream>>>(K8, v, accf, Pout_final, 3);
  for (int m=0;m<4;++m)
    lossfin2<<<1,256,0,stream>>>(accf + (size_t)m*NN, out + slotab[m]);

  sumloss<<<1,1,0,stream>>>(out);
}